// Round 2
// baseline (23220.432 us; speedup 1.0000x reference)
//
#include <hip/hip_runtime.h>
#include <math.h>

#define B_   64
#define T_   256
#define OUTD 1216
#define NBLK 64

typedef unsigned short ushort_t;
typedef unsigned int   uint32;
typedef __attribute__((ext_vector_type(8))) short bfrag;   // 8 bf16
typedef __attribute__((ext_vector_type(4))) float f32x4;
typedef __attribute__((ext_vector_type(4))) unsigned short us4;

__device__ __forceinline__ float sigmoidf_(float x) { return 1.0f / (1.0f + __expf(-x)); }
__device__ __forceinline__ float softplusf_(float x) { return (x > 20.0f) ? x : log1pf(__expf(x)); }
__device__ __forceinline__ ushort_t f2bf(float f) {
    uint32 u = __float_as_uint(f);
    u += 0x7fffu + ((u >> 16) & 1u);
    return (ushort_t)(u >> 16);
}
__device__ __forceinline__ float bf2f(ushort_t u) { return __uint_as_float(((uint32)u) << 16); }

// ---------------------------------------------------------------------------
// kwprep: one-time weight conversion (+ zero the grid-barrier counter so each
// graph replay starts clean).
// ---------------------------------------------------------------------------
__global__ void kwprep(const float* __restrict__ Wih, const float* __restrict__ Whh,
                       const float* __restrict__ Wp1, const float* __restrict__ Wq1,
                       const float* __restrict__ Wp2, const float* __restrict__ Wq2,
                       const float* __restrict__ Wsa,
                       ushort_t* Wih_b, ushort_t* Whh_b, ushort_t* Wp1_b, ushort_t* Wq1_b,
                       ushort_t* W2sw, ushort_t* Wsasw, unsigned* barcnt) {
    int stride = gridDim.x * blockDim.x;
    int gid = blockIdx.x * blockDim.x + threadIdx.x;
    if (gid == 0) *barcnt = 0u;
    for (int i = gid; i < 3072 * 1024; i += stride) Wih_b[i] = f2bf(Wih[i]);
    for (int i = gid; i < 3072 * 1024; i += stride) Whh_b[i] = f2bf(Whh[i]);
    for (int i = gid; i < 512 * 1024; i += stride) Wp1_b[i] = f2bf(Wp1[i]);
    for (int i = gid; i < 512 * 2048; i += stride) Wq1_b[i] = f2bf(Wq1[i]);
    for (int i = gid; i < 65536; i += stride) {
        int head = i >> 15, g = (i >> 9) & 63, o = (i >> 3) & 63, ii = i & 7;
        const float* src = head ? Wq2 : Wp2;
        W2sw[i] = f2bf(src[o * 512 + g * 8 + ii]);
    }
    for (int i = gid; i < 98304; i += stride) {
        int g = i >> 13, j = (i >> 3) & 1023, ii = i & 7;
        Wsasw[i] = f2bf(Wsa[j * 96 + g * 8 + ii]);
    }
}

// ---------------------------------------------------------------------------
// Grid barrier: monotonic counter, agent scope. All 64 blocks co-resident
// (1 block/CU, 48 KB LDS < 160 KB). Release add pairs with acquire spin-load.
// ---------------------------------------------------------------------------
__device__ __forceinline__ void gbar(unsigned* cnt, unsigned& ep) {
    __threadfence();
    __syncthreads();
    ++ep;
    if (threadIdx.x == 0) {
        __hip_atomic_fetch_add(cnt, 1u, __ATOMIC_RELEASE, __HIP_MEMORY_SCOPE_AGENT);
        unsigned tgt = ep * (unsigned)NBLK;
        while (__hip_atomic_load(cnt, __ATOMIC_ACQUIRE, __HIP_MEMORY_SCOPE_AGENT) < tgt)
            __builtin_amdgcn_s_sleep(2);
    }
    __syncthreads();
}

// ---------------------------------------------------------------------------
// krssm: the whole T=256 rollout in ONE persistent kernel.
//   prologue: emb(0) (stoch0=0), zero det buffers, swizzle obs(:,0,:)
//   loop t:  A) GRU (this block's 16-j slice)        -> bar
//            B) pm1/qm1 hidden matmuls               -> bar
//            C) heads + stats + emb(t+1) + obs(t+1)  -> bar
// ---------------------------------------------------------------------------
__global__ __launch_bounds__(256, 1) void krssm(
        const float* __restrict__ obs, const float* __restrict__ act,
        const float* __restrict__ n_p, const float* __restrict__ n_q,
        const float* __restrict__ Wsa, const float* __restrict__ bsa,
        const ushort_t* __restrict__ Wih, const ushort_t* __restrict__ Whh,
        const float* __restrict__ bih, const float* __restrict__ bhh,
        const ushort_t* __restrict__ Wp1b, const float* __restrict__ bp1,
        const ushort_t* __restrict__ Wq1b, const float* __restrict__ bq1,
        const ushort_t* __restrict__ W2sw, const ushort_t* __restrict__ Wsasw,
        const float* __restrict__ bp2, const float* __restrict__ bq2,
        ushort_t* emb_sw, ushort_t* obs_sw,
        ushort_t* det_sw0, ushort_t* det_sw1, float* det_fp0, float* det_fp1,
        float* pm1, float* qm1, float* out, unsigned* barcnt) {
    __shared__ float red[2 * 24 * 256];   // 48 KB, reused by all phases
    const int tid = threadIdx.x;
    const int blk = blockIdx.x;
    unsigned ep = 0;

    // ---- prologue ----
    for (int idx = blk * 256 + tid; idx < 65536; idx += NBLK * 256) {
        int j = idx >> 6, b = idx & 63;
        float acc = bsa[j];
        const float* a = act + (size_t)b * T_ * 64;
        const float* w = Wsa + j * 96 + 32;
#pragma unroll 8
        for (int c = 0; c < 64; ++c) acc += a[c] * w[c];
        emb_sw[((j >> 3) * 64 + b) * 8 + (j & 7)] = f2bf(fmaxf(acc, 0.f));
        det_sw0[idx] = 0;
        det_fp0[idx] = 0.f;
    }
    if (tid < 128) {   // swizzle obs(:, t=0, :) — block blk owns batch row blk
        int g = tid;
        const float* src = obs + (size_t)blk * T_ * 1024 + g * 8;
        bfrag v;
#pragma unroll
        for (int i = 0; i < 8; ++i) v[i] = (short)f2bf(src[i]);
        *(bfrag*)(obs_sw + ((size_t)g * 64 + blk) * 8) = v;
    }
    gbar(barcnt, ep);

    ushort_t* dsw_in = det_sw0; ushort_t* dsw_out = det_sw1;
    float* dfp_in = det_fp0;    float* dfp_out = det_fp1;

#pragma unroll 1
    for (int t = 0; t < T_; ++t) {
        // ================= phase A: GRU =================
        {
            const int lane = tid & 63, w = tid >> 6;
            const int m = lane & 15, quad = lane >> 4;
            const int j0 = blk * 16;

            f32x4 acc[2][3][4];
#pragma unroll
            for (int a2 = 0; a2 < 2; ++a2)
#pragma unroll
                for (int g = 0; g < 3; ++g)
#pragma unroll
                    for (int n = 0; n < 4; ++n) acc[a2][g][n] = (f32x4){0.f, 0.f, 0.f, 0.f};

            const int kb0 = w * 256;
            const ushort_t* arow[2][3];
#pragma unroll
            for (int g = 0; g < 3; ++g) {
                arow[0][g] = Wih + (size_t)(g * 1024 + j0 + m) * 1024 + kb0 + quad * 8;
                arow[1][g] = Whh + (size_t)(g * 1024 + j0 + m) * 1024 + kb0 + quad * 8;
            }
            const ushort_t* bx = emb_sw + ((kb0 >> 3) + quad) * 512 + m * 8;
            const ushort_t* bh = dsw_in + ((kb0 >> 3) + quad) * 512 + m * 8;

#pragma unroll
            for (int it = 0; it < 8; ++it) {
                bfrag a[2][3], vx[4], vh[4];
#pragma unroll
                for (int g = 0; g < 3; ++g) {
                    a[0][g] = *(const bfrag*)(arow[0][g] + it * 32);
                    a[1][g] = *(const bfrag*)(arow[1][g] + it * 32);
                }
#pragma unroll
                for (int n = 0; n < 4; ++n) {
                    vx[n] = *(const bfrag*)(bx + it * 2048 + n * 128);
                    vh[n] = *(const bfrag*)(bh + it * 2048 + n * 128);
                }
#pragma unroll
                for (int g = 0; g < 3; ++g)
#pragma unroll
                    for (int n = 0; n < 4; ++n) {
                        acc[0][g][n] = __builtin_amdgcn_mfma_f32_16x16x32_bf16(a[0][g], vx[n], acc[0][g][n], 0, 0, 0);
                        acc[1][g][n] = __builtin_amdgcn_mfma_f32_16x16x32_bf16(a[1][g], vh[n], acc[1][g][n], 0, 0, 0);
                    }
            }

            // two-phase cross-wave reduction (waves 1,3 dump; waves 0,2 add)
            if (w & 1) {
                float* dst = red + (w >> 1) * 6144;
#pragma unroll
                for (int a2 = 0; a2 < 2; ++a2)
#pragma unroll
                    for (int g = 0; g < 3; ++g)
#pragma unroll
                        for (int n = 0; n < 4; ++n)
                            *(f32x4*)(dst + ((a2 * 3 + g) * 4 + n) * 256 + lane * 4) = acc[a2][g][n];
            }
            __syncthreads();
            if (!(w & 1)) {
                float* dst = red + (w >> 1) * 6144;
#pragma unroll
                for (int a2 = 0; a2 < 2; ++a2)
#pragma unroll
                    for (int g = 0; g < 3; ++g)
#pragma unroll
                        for (int n = 0; n < 4; ++n) {
                            float* pp = dst + ((a2 * 3 + g) * 4 + n) * 256 + lane * 4;
                            f32x4 v = *(const f32x4*)pp;
                            v += acc[a2][g][n];
                            *(f32x4*)pp = v;
                        }
            }
            __syncthreads();

            // gate phase: thread -> (b = tid>>2, jq = tid&3)
            int b = tid >> 2, jq = tid & 3;
            int nt = b >> 4, bl = b & 15;
            int lsrc = (jq * 16 + bl) * 4;
            float gg[2][3][4];
#pragma unroll
            for (int a2 = 0; a2 < 2; ++a2)
#pragma unroll
                for (int g = 0; g < 3; ++g) {
                    f32x4 v0 = *(const f32x4*)(red + ((a2 * 3 + g) * 4 + nt) * 256 + lsrc);
                    f32x4 v1 = *(const f32x4*)(red + 6144 + ((a2 * 3 + g) * 4 + nt) * 256 + lsrc);
#pragma unroll
                    for (int i = 0; i < 4; ++i) gg[a2][g][i] = v0[i] + v1[i];
                }
            f32x4 bi[3], bh2[3];
#pragma unroll
            for (int g = 0; g < 3; ++g) {
                bi[g] = *(const f32x4*)(bih + g * 1024 + j0 + jq * 4);
                bh2[g] = *(const f32x4*)(bhh + g * 1024 + j0 + jq * 4);
            }
            f32x4 h4;
            us4 dq;
#pragma unroll
            for (int i = 0; i < 4; ++i) {
                int j = j0 + jq * 4 + i;
                float r = sigmoidf_(gg[0][0][i] + bi[0][i] + gg[1][0][i] + bh2[0][i]);
                float z = sigmoidf_(gg[0][1][i] + bi[1][i] + gg[1][1][i] + bh2[1][i]);
                float n = tanhf(gg[0][2][i] + bi[2][i] + r * (gg[1][2][i] + bh2[2][i]));
                float hp = dfp_in[j * 64 + b];
                float h = (1.f - z) * n + z * hp;
                h4[i] = h;
                dq[i] = f2bf(h);
                dfp_out[j * 64 + b] = h;
            }
            *(f32x4*)(out + ((size_t)b * T_ + t) * OUTD + j0 + jq * 4) = h4;
            int kbase = j0 + jq * 4;
            *(us4*)(dsw_out + ((kbase >> 3) * 64 + b) * 8 + (kbase & 7)) = dq;
        }
        gbar(barcnt, ep);

        // ================= phase B: pm1 / qm1 =================
        {
            const int lane = tid & 63, w = tid >> 6;
            const int m = lane & 15, quad = lane >> 4;
            const bool isq = blk >= 32;
            const int j0 = (isq ? blk - 32 : blk) * 16;

            f32x4 acc[4];
#pragma unroll
            for (int n = 0; n < 4; ++n) acc[n] = (f32x4){0.f, 0.f, 0.f, 0.f};

            if (!isq) {
                const ushort_t* ar = Wp1b + (size_t)(j0 + m) * 1024 + w * 256 + quad * 8;
                const ushort_t* bb = dsw_out + ((w * 32) + quad) * 512 + m * 8;
#pragma unroll
                for (int it = 0; it < 8; ++it) {
                    bfrag a = *(const bfrag*)(ar + it * 32);
#pragma unroll
                    for (int n = 0; n < 4; ++n) {
                        bfrag v = *(const bfrag*)(bb + it * 2048 + n * 128);
                        acc[n] = __builtin_amdgcn_mfma_f32_16x16x32_bf16(a, v, acc[n], 0, 0, 0);
                    }
                }
            } else {
                int kb0 = w * 512;
                const ushort_t* bsrc = (w < 2) ? dsw_out : obs_sw;
                int kloc = (w < 2) ? kb0 : kb0 - 1024;
                const ushort_t* ar = Wq1b + (size_t)(j0 + m) * 2048 + kb0 + quad * 8;
                const ushort_t* bb = bsrc + ((kloc >> 3) + quad) * 512 + m * 8;
#pragma unroll
                for (int it = 0; it < 16; ++it) {
                    bfrag a = *(const bfrag*)(ar + it * 32);
#pragma unroll
                    for (int n = 0; n < 4; ++n) {
                        bfrag v = *(const bfrag*)(bb + it * 2048 + n * 128);
                        acc[n] = __builtin_amdgcn_mfma_f32_16x16x32_bf16(a, v, acc[n], 0, 0, 0);
                    }
                }
            }
#pragma unroll
            for (int n = 0; n < 4; ++n)
                *(f32x4*)(red + (w * 4 + n) * 256 + lane * 4) = acc[n];
            __syncthreads();

            int b = tid >> 2, jq = tid & 3;
            int nt = b >> 4, lsrc = (jq * 16 + (b & 15)) * 4;
            f32x4 s = (f32x4){0.f, 0.f, 0.f, 0.f};
#pragma unroll
            for (int w2 = 0; w2 < 4; ++w2) s += *(const f32x4*)(red + (w2 * 4 + nt) * 256 + lsrc);
            f32x4 bv = *(const f32x4*)((isq ? bq1 : bp1) + j0 + jq * 4);
            f32x4 r;
#pragma unroll
            for (int i = 0; i < 4; ++i) r[i] = fmaxf(s[i] + bv[i], 0.f);
            *(f32x4*)((isq ? qm1 : pm1) + (size_t)b * 512 + j0 + jq * 4) = r;
        }
        gbar(barcnt, ep);

        // ================= phase C: heads + stats + emb(t+1) + obs(t+1) =====
        {
            float* s_p = red;
            float* s_q = red + 512;
            float* s_head = red + 1024;
            float* s_in = red + 1152;   // [0,32) stoch, [32,96) act(t+1)
            const int b = blk;
            if (tid < 128) ((f32x4*)s_p)[tid] = ((const f32x4*)(pm1 + (size_t)b * 512))[tid];
            else ((f32x4*)s_q)[tid - 128] = ((const f32x4*)(qm1 + (size_t)b * 512))[tid - 128];
            if (t + 1 < T_ && tid < 64) s_in[32 + tid] = act[((size_t)b * T_ + t + 1) * 64 + tid];
            if (t + 1 < T_ && tid >= 128) {   // swizzle obs(:, t+1, :) row b
                int g = tid - 128;            // [0,128) — ONE k-group per thread
                const float* src0 = obs + ((size_t)b * T_ + t + 1) * 1024 + g * 8;
                bfrag v0;
#pragma unroll
                for (int i = 0; i < 8; ++i) v0[i] = (short)f2bf(src0[i]);
                *(bfrag*)(obs_sw + ((size_t)g * 64 + b) * 8) = v0;
            }
            __syncthreads();
            if (tid < 128) {
                int head = tid >> 6, o = tid & 63;
                const ushort_t* wp = W2sw + head * 32768 + o * 8;
                const float* hv = head ? s_q : s_p;
                float acc2 = (head ? bq2 : bp2)[o];
#pragma unroll 4
                for (int g = 0; g < 64; ++g) {
                    bfrag w8 = *(const bfrag*)(wp + g * 512);
#pragma unroll
                    for (int i2 = 0; i2 < 8; ++i2) acc2 += hv[g * 8 + i2] * bf2f((ushort_t)w8[i2]);
                }
                s_head[tid] = acc2;
            }
            __syncthreads();
            if (tid < 64) {
                int s = tid & 31, isq = tid >> 5;
                float mean = s_head[isq * 64 + s];
                float raw = s_head[isq * 64 + 32 + s];
                float sd = softplusf_(raw) + 1e-5f;
                float noise = (isq ? n_q : n_p)[((size_t)b * T_ + t) * 32 + s];
                float st = mean + sd * noise;
                float* o = out + ((size_t)b * T_ + t) * OUTD + 1024 + isq * 96;
                o[s] = mean;
                o[32 + s] = sd;
                o[64 + s] = st;
                if (isq) s_in[s] = st;
            }
            __syncthreads();
            if (t + 1 < T_) {
#pragma unroll
                for (int q = 0; q < 4; ++q) {
                    int j = q * 256 + tid;
                    float acc2 = bsa[j];
#pragma unroll
                    for (int g = 0; g < 12; ++g) {
                        bfrag w8 = *(const bfrag*)(Wsasw + ((size_t)g * 1024 + j) * 8);
#pragma unroll
                        for (int i2 = 0; i2 < 8; ++i2) acc2 += s_in[g * 8 + i2] * bf2f((ushort_t)w8[i2]);
                    }
                    emb_sw[((j >> 3) * 64 + b) * 8 + (j & 7)] = f2bf(fmaxf(acc2, 0.f));
                }
            }
        }
        gbar(barcnt, ep);

        // swap det ping-pong
        ushort_t* ts = dsw_in; dsw_in = dsw_out; dsw_out = ts;
        float* tf = dfp_in; dfp_in = dfp_out; dfp_out = tf;
    }
}

extern "C" void kernel_launch(void* const* d_in, const int* in_sizes, int n_in,
                              void* d_out, int out_size, void* d_ws, size_t ws_size,
                              hipStream_t stream) {
    const float* obs = (const float*)d_in[0];
    const float* act = (const float*)d_in[1];
    const float* n_p = (const float*)d_in[2];
    const float* n_q = (const float*)d_in[3];
    const float* W_sa = (const float*)d_in[4];
    const float* b_sa = (const float*)d_in[5];
    const float* W_ih = (const float*)d_in[6];
    const float* b_ih = (const float*)d_in[7];
    const float* W_hh = (const float*)d_in[8];
    const float* b_hh = (const float*)d_in[9];
    const float* Wp1 = (const float*)d_in[10];
    const float* bp1 = (const float*)d_in[11];
    const float* Wp2 = (const float*)d_in[12];
    const float* bp2 = (const float*)d_in[13];
    const float* Wq1 = (const float*)d_in[14];
    const float* bq1 = (const float*)d_in[15];
    const float* Wq2 = (const float*)d_in[16];
    const float* bq2 = (const float*)d_in[17];
    float* out = (float*)d_out;

    char* p = (char*)d_ws;
    ushort_t* Wih_b = (ushort_t*)p;  p += (size_t)3145728 * 2;
    ushort_t* Whh_b = (ushort_t*)p;  p += (size_t)3145728 * 2;
    ushort_t* Wp1_b = (ushort_t*)p;  p += (size_t)524288 * 2;
    ushort_t* Wq1_b = (ushort_t*)p;  p += (size_t)1048576 * 2;
    ushort_t* W2sw  = (ushort_t*)p;  p += (size_t)65536 * 2;
    ushort_t* Wsasw = (ushort_t*)p;  p += (size_t)98304 * 2;
    ushort_t* emb_sw = (ushort_t*)p; p += (size_t)65536 * 2;
    ushort_t* obs_sw = (ushort_t*)p; p += (size_t)65536 * 2;
    ushort_t* det_sw0 = (ushort_t*)p; p += (size_t)65536 * 2;
    ushort_t* det_sw1 = (ushort_t*)p; p += (size_t)65536 * 2;
    float* det_fp0 = (float*)p; p += (size_t)65536 * 4;
    float* det_fp1 = (float*)p; p += (size_t)65536 * 4;
    float* pm1 = (float*)p; p += (size_t)32768 * 4;
    float* qm1 = (float*)p; p += (size_t)32768 * 4;
    unsigned* barcnt = (unsigned*)p; p += 256;

    kwprep<<<1024, 256, 0, stream>>>(W_ih, W_hh, Wp1, Wq1, Wp2, Wq2, W_sa,
                                     Wih_b, Whh_b, Wp1_b, Wq1_b, W2sw, Wsasw, barcnt);
    krssm<<<NBLK, 256, 0, stream>>>(obs, act, n_p, n_q, W_sa, b_sa,
                                    Wih_b, Whh_b, b_ih, b_hh,
                                    Wp1_b, bp1, Wq1_b, bq1,
                                    W2sw, Wsasw, bp2, bq2,
                                    emb_sw, obs_sw, det_sw0, det_sw1,
                                    det_fp0, det_fp1, pm1, qm1, out, barcnt);
}

// Round 3
// 18194.032 us; speedup vs baseline: 1.2763x; 1.2763x over previous
//
#include <hip/hip_runtime.h>
#include <math.h>

#define B_   64
#define T_   256
#define OUTD 1216
#define NBLK 64

typedef unsigned short ushort_t;
typedef unsigned int   uint32;
typedef __attribute__((ext_vector_type(8))) short bfrag;   // 8 bf16
typedef __attribute__((ext_vector_type(4))) float f32x4;
typedef __attribute__((ext_vector_type(4))) unsigned short us4;

__device__ __forceinline__ float sigmoidf_(float x) { return 1.0f / (1.0f + __expf(-x)); }
__device__ __forceinline__ float softplusf_(float x) { return (x > 20.0f) ? x : log1pf(__expf(x)); }
__device__ __forceinline__ ushort_t f2bf(float f) {
    uint32 u = __float_as_uint(f);
    u += 0x7fffu + ((u >> 16) & 1u);
    return (ushort_t)(u >> 16);
}
__device__ __forceinline__ float bf2f(ushort_t u) { return __uint_as_float(((uint32)u) << 16); }

// ---------------------------------------------------------------------------
// kwprep: one-time weight conversion (+ zero the grid-barrier counter so each
// graph replay starts clean).
// ---------------------------------------------------------------------------
__global__ void kwprep(const float* __restrict__ Wih, const float* __restrict__ Whh,
                       const float* __restrict__ Wp1, const float* __restrict__ Wq1,
                       const float* __restrict__ Wp2, const float* __restrict__ Wq2,
                       const float* __restrict__ Wsa,
                       ushort_t* Wih_b, ushort_t* Whh_b, ushort_t* Wp1_b, ushort_t* Wq1_b,
                       ushort_t* W2sw, ushort_t* Wsasw, unsigned* barcnt) {
    int stride = gridDim.x * blockDim.x;
    int gid = blockIdx.x * blockDim.x + threadIdx.x;
    if (gid == 0) *barcnt = 0u;
    for (int i = gid; i < 3072 * 1024; i += stride) Wih_b[i] = f2bf(Wih[i]);
    for (int i = gid; i < 3072 * 1024; i += stride) Whh_b[i] = f2bf(Whh[i]);
    for (int i = gid; i < 512 * 1024; i += stride) Wp1_b[i] = f2bf(Wp1[i]);
    for (int i = gid; i < 512 * 2048; i += stride) Wq1_b[i] = f2bf(Wq1[i]);
    for (int i = gid; i < 65536; i += stride) {
        int head = i >> 15, g = (i >> 9) & 63, o = (i >> 3) & 63, ii = i & 7;
        const float* src = head ? Wq2 : Wp2;
        W2sw[i] = f2bf(src[o * 512 + g * 8 + ii]);
    }
    for (int i = gid; i < 98304; i += stride) {
        int g = i >> 13, j = (i >> 3) & 1023, ii = i & 7;
        Wsasw[i] = f2bf(Wsa[j * 96 + g * 8 + ii]);
    }
}

// ---------------------------------------------------------------------------
// Grid barrier, two-phase. KEY: the spin uses RELAXED loads (no cache
// maintenance per poll); exactly ONE release (buffer_wbl2) at arrive and ONE
// acquire fence (buffer_inv) after the spin exits. The previous version had
// the acquire INSIDE the poll loop -> L2-invalidate storm (30 us/barrier,
// VALUBusy 1.2%).
// ---------------------------------------------------------------------------
__device__ __forceinline__ void gbar(unsigned* cnt, unsigned& ep) {
    __syncthreads();   // compiler emits s_waitcnt vmcnt(0) before s_barrier:
                       // all threads' stores are drained to L2 here
    ++ep;
    if (threadIdx.x == 0) {
        __hip_atomic_fetch_add(cnt, 1u, __ATOMIC_RELEASE, __HIP_MEMORY_SCOPE_AGENT);
        unsigned tgt = ep * (unsigned)NBLK;
        while (__hip_atomic_load(cnt, __ATOMIC_RELAXED, __HIP_MEMORY_SCOPE_AGENT) < tgt)
            __builtin_amdgcn_s_sleep(2);
        __builtin_amdgcn_fence(__ATOMIC_ACQUIRE, "agent");   // one buffer_inv
    }
    __syncthreads();
}

// ---------------------------------------------------------------------------
// krssm: the whole T=256 rollout in ONE persistent kernel.
//   prologue: emb(0) (stoch0=0), zero det buffers, swizzle obs(:,0,:)
//   loop t:  A) GRU (this block's 16-j slice)        -> bar
//            B) pm1/qm1 hidden matmuls               -> bar
//            C) heads + stats + emb(t+1) + obs(t+1)  -> bar
// ---------------------------------------------------------------------------
__global__ __launch_bounds__(256, 1) void krssm(
        const float* __restrict__ obs, const float* __restrict__ act,
        const float* __restrict__ n_p, const float* __restrict__ n_q,
        const float* __restrict__ Wsa, const float* __restrict__ bsa,
        const ushort_t* __restrict__ Wih, const ushort_t* __restrict__ Whh,
        const float* __restrict__ bih, const float* __restrict__ bhh,
        const ushort_t* __restrict__ Wp1b, const float* __restrict__ bp1,
        const ushort_t* __restrict__ Wq1b, const float* __restrict__ bq1,
        const ushort_t* __restrict__ W2sw, const ushort_t* __restrict__ Wsasw,
        const float* __restrict__ bp2, const float* __restrict__ bq2,
        ushort_t* emb_sw, ushort_t* obs_sw,
        ushort_t* det_sw0, ushort_t* det_sw1, float* det_fp0, float* det_fp1,
        float* pm1, float* qm1, float* out, unsigned* barcnt) {
    __shared__ float red[2 * 24 * 256];   // 48 KB, reused by all phases
    const int tid = threadIdx.x;
    const int blk = blockIdx.x;
    unsigned ep = 0;

    // ---- prologue ----
    for (int idx = blk * 256 + tid; idx < 65536; idx += NBLK * 256) {
        int j = idx >> 6, b = idx & 63;
        float acc = bsa[j];
        const float* a = act + (size_t)b * T_ * 64;
        const float* w = Wsa + j * 96 + 32;
#pragma unroll 8
        for (int c = 0; c < 64; ++c) acc += a[c] * w[c];
        emb_sw[((j >> 3) * 64 + b) * 8 + (j & 7)] = f2bf(fmaxf(acc, 0.f));
        det_sw0[idx] = 0;
        det_fp0[idx] = 0.f;
    }
    if (tid < 128) {   // swizzle obs(:, t=0, :) — block blk owns batch row blk
        int g = tid;
        const float* src = obs + (size_t)blk * T_ * 1024 + g * 8;
        bfrag v;
#pragma unroll
        for (int i = 0; i < 8; ++i) v[i] = (short)f2bf(src[i]);
        *(bfrag*)(obs_sw + ((size_t)g * 64 + blk) * 8) = v;
    }
    gbar(barcnt, ep);

    ushort_t* dsw_in = det_sw0; ushort_t* dsw_out = det_sw1;
    float* dfp_in = det_fp0;    float* dfp_out = det_fp1;

#pragma unroll 1
    for (int t = 0; t < T_; ++t) {
        // ================= phase A: GRU =================
        {
            const int lane = tid & 63, w = tid >> 6;
            const int m = lane & 15, quad = lane >> 4;
            const int j0 = blk * 16;

            f32x4 acc[2][3][4];
#pragma unroll
            for (int a2 = 0; a2 < 2; ++a2)
#pragma unroll
                for (int g = 0; g < 3; ++g)
#pragma unroll
                    for (int n = 0; n < 4; ++n) acc[a2][g][n] = (f32x4){0.f, 0.f, 0.f, 0.f};

            const int kb0 = w * 256;
            const ushort_t* arow[2][3];
#pragma unroll
            for (int g = 0; g < 3; ++g) {
                arow[0][g] = Wih + (size_t)(g * 1024 + j0 + m) * 1024 + kb0 + quad * 8;
                arow[1][g] = Whh + (size_t)(g * 1024 + j0 + m) * 1024 + kb0 + quad * 8;
            }
            const ushort_t* bx = emb_sw + ((kb0 >> 3) + quad) * 512 + m * 8;
            const ushort_t* bh = dsw_in + ((kb0 >> 3) + quad) * 512 + m * 8;

#pragma unroll
            for (int it = 0; it < 8; ++it) {
                bfrag a[2][3], vx[4], vh[4];
#pragma unroll
                for (int g = 0; g < 3; ++g) {
                    a[0][g] = *(const bfrag*)(arow[0][g] + it * 32);
                    a[1][g] = *(const bfrag*)(arow[1][g] + it * 32);
                }
#pragma unroll
                for (int n = 0; n < 4; ++n) {
                    vx[n] = *(const bfrag*)(bx + it * 2048 + n * 128);
                    vh[n] = *(const bfrag*)(bh + it * 2048 + n * 128);
                }
#pragma unroll
                for (int g = 0; g < 3; ++g)
#pragma unroll
                    for (int n = 0; n < 4; ++n) {
                        acc[0][g][n] = __builtin_amdgcn_mfma_f32_16x16x32_bf16(a[0][g], vx[n], acc[0][g][n], 0, 0, 0);
                        acc[1][g][n] = __builtin_amdgcn_mfma_f32_16x16x32_bf16(a[1][g], vh[n], acc[1][g][n], 0, 0, 0);
                    }
            }

            // two-phase cross-wave reduction (waves 1,3 dump; waves 0,2 add)
            if (w & 1) {
                float* dst = red + (w >> 1) * 6144;
#pragma unroll
                for (int a2 = 0; a2 < 2; ++a2)
#pragma unroll
                    for (int g = 0; g < 3; ++g)
#pragma unroll
                        for (int n = 0; n < 4; ++n)
                            *(f32x4*)(dst + ((a2 * 3 + g) * 4 + n) * 256 + lane * 4) = acc[a2][g][n];
            }
            __syncthreads();
            if (!(w & 1)) {
                float* dst = red + (w >> 1) * 6144;
#pragma unroll
                for (int a2 = 0; a2 < 2; ++a2)
#pragma unroll
                    for (int g = 0; g < 3; ++g)
#pragma unroll
                        for (int n = 0; n < 4; ++n) {
                            float* pp = dst + ((a2 * 3 + g) * 4 + n) * 256 + lane * 4;
                            f32x4 v = *(const f32x4*)pp;
                            v += acc[a2][g][n];
                            *(f32x4*)pp = v;
                        }
            }
            __syncthreads();

            // gate phase: thread -> (b = tid>>2, jq = tid&3)
            int b = tid >> 2, jq = tid & 3;
            int nt = b >> 4, bl = b & 15;
            int lsrc = (jq * 16 + bl) * 4;
            float gg[2][3][4];
#pragma unroll
            for (int a2 = 0; a2 < 2; ++a2)
#pragma unroll
                for (int g = 0; g < 3; ++g) {
                    f32x4 v0 = *(const f32x4*)(red + ((a2 * 3 + g) * 4 + nt) * 256 + lsrc);
                    f32x4 v1 = *(const f32x4*)(red + 6144 + ((a2 * 3 + g) * 4 + nt) * 256 + lsrc);
#pragma unroll
                    for (int i = 0; i < 4; ++i) gg[a2][g][i] = v0[i] + v1[i];
                }
            f32x4 bi[3], bh2[3];
#pragma unroll
            for (int g = 0; g < 3; ++g) {
                bi[g] = *(const f32x4*)(bih + g * 1024 + j0 + jq * 4);
                bh2[g] = *(const f32x4*)(bhh + g * 1024 + j0 + jq * 4);
            }
            f32x4 h4;
            us4 dq;
#pragma unroll
            for (int i = 0; i < 4; ++i) {
                int j = j0 + jq * 4 + i;
                float r = sigmoidf_(gg[0][0][i] + bi[0][i] + gg[1][0][i] + bh2[0][i]);
                float z = sigmoidf_(gg[0][1][i] + bi[1][i] + gg[1][1][i] + bh2[1][i]);
                float n = tanhf(gg[0][2][i] + bi[2][i] + r * (gg[1][2][i] + bh2[2][i]));
                float hp = dfp_in[j * 64 + b];
                float h = (1.f - z) * n + z * hp;
                h4[i] = h;
                dq[i] = f2bf(h);
                dfp_out[j * 64 + b] = h;
            }
            *(f32x4*)(out + ((size_t)b * T_ + t) * OUTD + j0 + jq * 4) = h4;
            int kbase = j0 + jq * 4;
            *(us4*)(dsw_out + ((kbase >> 3) * 64 + b) * 8 + (kbase & 7)) = dq;
        }
        gbar(barcnt, ep);

        // ================= phase B: pm1 / qm1 =================
        {
            const int lane = tid & 63, w = tid >> 6;
            const int m = lane & 15, quad = lane >> 4;
            const bool isq = blk >= 32;
            const int j0 = (isq ? blk - 32 : blk) * 16;

            f32x4 acc[4];
#pragma unroll
            for (int n = 0; n < 4; ++n) acc[n] = (f32x4){0.f, 0.f, 0.f, 0.f};

            if (!isq) {
                const ushort_t* ar = Wp1b + (size_t)(j0 + m) * 1024 + w * 256 + quad * 8;
                const ushort_t* bb = dsw_out + ((w * 32) + quad) * 512 + m * 8;
#pragma unroll
                for (int it = 0; it < 8; ++it) {
                    bfrag a = *(const bfrag*)(ar + it * 32);
#pragma unroll
                    for (int n = 0; n < 4; ++n) {
                        bfrag v = *(const bfrag*)(bb + it * 2048 + n * 128);
                        acc[n] = __builtin_amdgcn_mfma_f32_16x16x32_bf16(a, v, acc[n], 0, 0, 0);
                    }
                }
            } else {
                int kb0 = w * 512;
                const ushort_t* bsrc = (w < 2) ? dsw_out : obs_sw;
                int kloc = (w < 2) ? kb0 : kb0 - 1024;
                const ushort_t* ar = Wq1b + (size_t)(j0 + m) * 2048 + kb0 + quad * 8;
                const ushort_t* bb = bsrc + ((kloc >> 3) + quad) * 512 + m * 8;
#pragma unroll
                for (int it = 0; it < 16; ++it) {
                    bfrag a = *(const bfrag*)(ar + it * 32);
#pragma unroll
                    for (int n = 0; n < 4; ++n) {
                        bfrag v = *(const bfrag*)(bb + it * 2048 + n * 128);
                        acc[n] = __builtin_amdgcn_mfma_f32_16x16x32_bf16(a, v, acc[n], 0, 0, 0);
                    }
                }
            }
#pragma unroll
            for (int n = 0; n < 4; ++n)
                *(f32x4*)(red + (w * 4 + n) * 256 + lane * 4) = acc[n];
            __syncthreads();

            int b = tid >> 2, jq = tid & 3;
            int nt = b >> 4, lsrc = (jq * 16 + (b & 15)) * 4;
            f32x4 s = (f32x4){0.f, 0.f, 0.f, 0.f};
#pragma unroll
            for (int w2 = 0; w2 < 4; ++w2) s += *(const f32x4*)(red + (w2 * 4 + nt) * 256 + lsrc);
            f32x4 bv = *(const f32x4*)((isq ? bq1 : bp1) + j0 + jq * 4);
            f32x4 r;
#pragma unroll
            for (int i = 0; i < 4; ++i) r[i] = fmaxf(s[i] + bv[i], 0.f);
            *(f32x4*)((isq ? qm1 : pm1) + (size_t)b * 512 + j0 + jq * 4) = r;
        }
        gbar(barcnt, ep);

        // ================= phase C: heads + stats + emb(t+1) + obs(t+1) =====
        {
            float* s_p = red;
            float* s_q = red + 512;
            float* s_head = red + 1024;
            float* s_in = red + 1152;   // [0,32) stoch, [32,96) act(t+1)
            const int b = blk;
            if (tid < 128) ((f32x4*)s_p)[tid] = ((const f32x4*)(pm1 + (size_t)b * 512))[tid];
            else ((f32x4*)s_q)[tid - 128] = ((const f32x4*)(qm1 + (size_t)b * 512))[tid - 128];
            if (t + 1 < T_ && tid < 64) s_in[32 + tid] = act[((size_t)b * T_ + t + 1) * 64 + tid];
            if (t + 1 < T_ && tid >= 128) {   // swizzle obs(:, t+1, :) row b
                int g = tid - 128;            // [0,128) — ONE k-group per thread
                const float* src0 = obs + ((size_t)b * T_ + t + 1) * 1024 + g * 8;
                bfrag v0;
#pragma unroll
                for (int i = 0; i < 8; ++i) v0[i] = (short)f2bf(src0[i]);
                *(bfrag*)(obs_sw + ((size_t)g * 64 + b) * 8) = v0;
            }
            __syncthreads();
            if (tid < 128) {
                int head = tid >> 6, o = tid & 63;
                const ushort_t* wp = W2sw + head * 32768 + o * 8;
                const float* hv = head ? s_q : s_p;
                float acc2 = (head ? bq2 : bp2)[o];
#pragma unroll 4
                for (int g = 0; g < 64; ++g) {
                    bfrag w8 = *(const bfrag*)(wp + g * 512);
#pragma unroll
                    for (int i2 = 0; i2 < 8; ++i2) acc2 += hv[g * 8 + i2] * bf2f((ushort_t)w8[i2]);
                }
                s_head[tid] = acc2;
            }
            __syncthreads();
            if (tid < 64) {
                int s = tid & 31, isq = tid >> 5;
                float mean = s_head[isq * 64 + s];
                float raw = s_head[isq * 64 + 32 + s];
                float sd = softplusf_(raw) + 1e-5f;
                float noise = (isq ? n_q : n_p)[((size_t)b * T_ + t) * 32 + s];
                float st = mean + sd * noise;
                float* o = out + ((size_t)b * T_ + t) * OUTD + 1024 + isq * 96;
                o[s] = mean;
                o[32 + s] = sd;
                o[64 + s] = st;
                if (isq) s_in[s] = st;
            }
            __syncthreads();
            if (t + 1 < T_) {
#pragma unroll
                for (int q = 0; q < 4; ++q) {
                    int j = q * 256 + tid;
                    float acc2 = bsa[j];
#pragma unroll
                    for (int g = 0; g < 12; ++g) {
                        bfrag w8 = *(const bfrag*)(Wsasw + ((size_t)g * 1024 + j) * 8);
#pragma unroll
                        for (int i2 = 0; i2 < 8; ++i2) acc2 += s_in[g * 8 + i2] * bf2f((ushort_t)w8[i2]);
                    }
                    emb_sw[((j >> 3) * 64 + b) * 8 + (j & 7)] = f2bf(fmaxf(acc2, 0.f));
                }
            }
        }
        gbar(barcnt, ep);

        // swap det ping-pong
        ushort_t* ts = dsw_in; dsw_in = dsw_out; dsw_out = ts;
        float* tf = dfp_in; dfp_in = dfp_out; dfp_out = tf;
    }
}

extern "C" void kernel_launch(void* const* d_in, const int* in_sizes, int n_in,
                              void* d_out, int out_size, void* d_ws, size_t ws_size,
                              hipStream_t stream) {
    const float* obs = (const float*)d_in[0];
    const float* act = (const float*)d_in[1];
    const float* n_p = (const float*)d_in[2];
    const float* n_q = (const float*)d_in[3];
    const float* W_sa = (const float*)d_in[4];
    const float* b_sa = (const float*)d_in[5];
    const float* W_ih = (const float*)d_in[6];
    const float* b_ih = (const float*)d_in[7];
    const float* W_hh = (const float*)d_in[8];
    const float* b_hh = (const float*)d_in[9];
    const float* Wp1 = (const float*)d_in[10];
    const float* bp1 = (const float*)d_in[11];
    const float* Wp2 = (const float*)d_in[12];
    const float* bp2 = (const float*)d_in[13];
    const float* Wq1 = (const float*)d_in[14];
    const float* bq1 = (const float*)d_in[15];
    const float* Wq2 = (const float*)d_in[16];
    const float* bq2 = (const float*)d_in[17];
    float* out = (float*)d_out;

    char* p = (char*)d_ws;
    ushort_t* Wih_b = (ushort_t*)p;  p += (size_t)3145728 * 2;
    ushort_t* Whh_b = (ushort_t*)p;  p += (size_t)3145728 * 2;
    ushort_t* Wp1_b = (ushort_t*)p;  p += (size_t)524288 * 2;
    ushort_t* Wq1_b = (ushort_t*)p;  p += (size_t)1048576 * 2;
    ushort_t* W2sw  = (ushort_t*)p;  p += (size_t)65536 * 2;
    ushort_t* Wsasw = (ushort_t*)p;  p += (size_t)98304 * 2;
    ushort_t* emb_sw = (ushort_t*)p; p += (size_t)65536 * 2;
    ushort_t* obs_sw = (ushort_t*)p; p += (size_t)65536 * 2;
    ushort_t* det_sw0 = (ushort_t*)p; p += (size_t)65536 * 2;
    ushort_t* det_sw1 = (ushort_t*)p; p += (size_t)65536 * 2;
    float* det_fp0 = (float*)p; p += (size_t)65536 * 4;
    float* det_fp1 = (float*)p; p += (size_t)65536 * 4;
    float* pm1 = (float*)p; p += (size_t)32768 * 4;
    float* qm1 = (float*)p; p += (size_t)32768 * 4;
    unsigned* barcnt = (unsigned*)p; p += 256;

    kwprep<<<1024, 256, 0, stream>>>(W_ih, W_hh, Wp1, Wq1, Wp2, Wq2, W_sa,
                                     Wih_b, Whh_b, Wp1_b, Wq1_b, W2sw, Wsasw, barcnt);
    krssm<<<NBLK, 256, 0, stream>>>(obs, act, n_p, n_q, W_sa, b_sa,
                                    Wih_b, Whh_b, b_ih, b_hh,
                                    Wp1_b, bp1, Wq1_b, bq1,
                                    W2sw, Wsasw, bp2, bq2,
                                    emb_sw, obs_sw, det_sw0, det_sw1,
                                    det_fp0, det_fp1, pm1, qm1, out, barcnt);
}

// Round 4
// 18137.741 us; speedup vs baseline: 1.2802x; 1.0031x over previous
//
#include <hip/hip_runtime.h>
#include <math.h>

#define B_   64
#define T_   256
#define OUTD 1216
#define NBLK 64

typedef unsigned short ushort_t;
typedef unsigned int   uint32;
typedef unsigned long long u64;
typedef __attribute__((ext_vector_type(8))) short bfrag;   // 8 bf16
typedef __attribute__((ext_vector_type(4))) float f32x4;
typedef __attribute__((ext_vector_type(4))) unsigned short us4;

#define SCOPE_AGT __HIP_MEMORY_SCOPE_AGENT

__device__ __forceinline__ float sigmoidf_(float x) { return 1.0f / (1.0f + __expf(-x)); }
__device__ __forceinline__ float softplusf_(float x) { return (x > 20.0f) ? x : log1pf(__expf(x)); }
__device__ __forceinline__ ushort_t f2bf(float f) {
    uint32 u = __float_as_uint(f);
    u += 0x7fffu + ((u >> 16) & 1u);
    return (ushort_t)(u >> 16);
}
__device__ __forceinline__ float bf2f(ushort_t u) { return __uint_as_float(((uint32)u) << 16); }

// ---------------------------------------------------------------------------
// Agent-coherent (cross-XCD) access helpers. RELAXED+AGENT atomics lower to
// global_load/store with sc1 — they bypass the per-XCD L2s and hit the
// coherent point directly. Only the ~600KB/step of cross-block activations
// use these; weights/biases/inputs stay on the normal cached path and remain
// L2-resident across the whole rollout (no per-barrier buffer_inv anymore).
// ---------------------------------------------------------------------------
union U16 { u64 q[2]; bfrag bv; f32x4 fv; };
union U8  { u64 q; us4 v4; };

__device__ __forceinline__ u64 ldc8(const void* p) {
    return __hip_atomic_load((const u64*)p, __ATOMIC_RELAXED, SCOPE_AGT);
}
__device__ __forceinline__ void stc8(void* p, u64 v) {
    __hip_atomic_store((u64*)p, v, __ATOMIC_RELAXED, SCOPE_AGT);
}
__device__ __forceinline__ bfrag ldc16b(const void* p) {
    U16 u; u.q[0] = ldc8(p); u.q[1] = ldc8((const u64*)p + 1); return u.bv;
}
__device__ __forceinline__ f32x4 ldc16f(const void* p) {
    U16 u; u.q[0] = ldc8(p); u.q[1] = ldc8((const u64*)p + 1); return u.fv;
}
__device__ __forceinline__ void stc16f(void* p, f32x4 v) {
    U16 u; u.fv = v; stc8(p, u.q[0]); stc8((u64*)p + 1, u.q[1]);
}
__device__ __forceinline__ void stc16b(void* p, bfrag v) {
    U16 u; u.bv = v; stc8(p, u.q[0]); stc8((u64*)p + 1, u.q[1]);
}

// ---------------------------------------------------------------------------
// kwprep: one-time weight conversion (+ zero the grid-barrier counter so each
// graph replay starts clean).
// ---------------------------------------------------------------------------
__global__ void kwprep(const float* __restrict__ Wih, const float* __restrict__ Whh,
                       const float* __restrict__ Wp1, const float* __restrict__ Wq1,
                       const float* __restrict__ Wp2, const float* __restrict__ Wq2,
                       const float* __restrict__ Wsa,
                       ushort_t* Wih_b, ushort_t* Whh_b, ushort_t* Wp1_b, ushort_t* Wq1_b,
                       ushort_t* W2sw, ushort_t* Wsasw, unsigned* barcnt) {
    int stride = gridDim.x * blockDim.x;
    int gid = blockIdx.x * blockDim.x + threadIdx.x;
    if (gid == 0) *barcnt = 0u;
    for (int i = gid; i < 3072 * 1024; i += stride) Wih_b[i] = f2bf(Wih[i]);
    for (int i = gid; i < 3072 * 1024; i += stride) Whh_b[i] = f2bf(Whh[i]);
    for (int i = gid; i < 512 * 1024; i += stride) Wp1_b[i] = f2bf(Wp1[i]);
    for (int i = gid; i < 512 * 2048; i += stride) Wq1_b[i] = f2bf(Wq1[i]);
    for (int i = gid; i < 65536; i += stride) {
        int head = i >> 15, g = (i >> 9) & 63, o = (i >> 3) & 63, ii = i & 7;
        const float* src = head ? Wq2 : Wp2;
        W2sw[i] = f2bf(src[o * 512 + g * 8 + ii]);
    }
    for (int i = gid; i < 98304; i += stride) {
        int g = i >> 13, j = (i >> 3) & 1023, ii = i & 7;
        Wsasw[i] = f2bf(Wsa[j * 96 + g * 8 + ii]);
    }
}

// ---------------------------------------------------------------------------
// Grid barrier, fence-free. Correctness argument: all cross-block data is
// written with sc1 (agent) stores; s_waitcnt vmcnt(0) means every such store
// has been ACK'd at the coherent point before this block's arrival is
// published. Readers use sc1 loads that also go to the coherent point, so no
// acquire-invalidate is needed — L2-cached weights survive all 769 barriers.
// (Previous version: release-RMW + acquire fence = buffer_wbl2 + buffer_inv
// per block per barrier -> every phase started with a cold L2; 23us/barrier.)
// ---------------------------------------------------------------------------
__device__ __forceinline__ void gbar(unsigned* cnt, unsigned& ep) {
    asm volatile("s_waitcnt vmcnt(0)" ::: "memory");
    __syncthreads();
    ++ep;
    if (threadIdx.x == 0) {
        __hip_atomic_fetch_add(cnt, 1u, __ATOMIC_RELAXED, SCOPE_AGT);
        unsigned tgt = ep * (unsigned)NBLK;
        while (__hip_atomic_load(cnt, __ATOMIC_RELAXED, SCOPE_AGT) < tgt)
            __builtin_amdgcn_s_sleep(2);
    }
    __syncthreads();
}

// ---------------------------------------------------------------------------
// krssm: the whole T=256 rollout in ONE persistent kernel.
//   prologue: emb(0) (stoch0=0), zero det buffers, swizzle obs(:,0,:)
//   loop t:  A) GRU (this block's 16-j slice)        -> bar
//            B) pm1/qm1 hidden matmuls               -> bar
//            C) heads + stats + emb(t+1) + obs(t+1)  -> bar
// Cross-block arrays (sc1 path): emb_sw, det_sw0/1, obs_sw, pm1, qm1.
// Block-private (cached path): det_fp (same j-slice producer/consumer), out.
// ---------------------------------------------------------------------------
__global__ __launch_bounds__(256, 1) void krssm(
        const float* __restrict__ obs, const float* __restrict__ act,
        const float* __restrict__ n_p, const float* __restrict__ n_q,
        const float* __restrict__ Wsa, const float* __restrict__ bsa,
        const ushort_t* __restrict__ Wih, const ushort_t* __restrict__ Whh,
        const float* __restrict__ bih, const float* __restrict__ bhh,
        const ushort_t* __restrict__ Wp1b, const float* __restrict__ bp1,
        const ushort_t* __restrict__ Wq1b, const float* __restrict__ bq1,
        const ushort_t* __restrict__ W2sw, const ushort_t* __restrict__ Wsasw,
        const float* __restrict__ bp2, const float* __restrict__ bq2,
        ushort_t* emb_sw, ushort_t* obs_sw,
        ushort_t* det_sw0, ushort_t* det_sw1, float* det_fp0, float* det_fp1,
        float* pm1, float* qm1, float* out, unsigned* barcnt) {
    __shared__ float red[2 * 24 * 256];   // 48 KB, reused by all phases
    const int tid = threadIdx.x;
    const int blk = blockIdx.x;
    unsigned ep = 0;

    // ---- prologue: block blk owns batch row b=blk for emb(0)/obs(0);
    //      each thread covers 4 CONSECUTIVE j so the swizzled store is one
    //      aligned 8B coherent store. det_fp0: zero OWN j-slice (private). ----
    {
        const int b = blk;
        const int j0 = tid * 4;
        const float* arow_ = act + (size_t)b * T_ * 64;
        float accp[4];
#pragma unroll
        for (int jj = 0; jj < 4; ++jj) {
            int j = j0 + jj;
            float acc = bsa[j];
            const float* w = Wsa + j * 96 + 32;
#pragma unroll 8
            for (int c = 0; c < 64; ++c) acc += arow_[c] * w[c];
            accp[jj] = fmaxf(acc, 0.f);
        }
        U8 u;
#pragma unroll
        for (int jj = 0; jj < 4; ++jj) u.v4[jj] = f2bf(accp[jj]);
        size_t eoff = ((size_t)(j0 >> 3) * 64 + b) * 8 + (j0 & 7);
        stc8(emb_sw + eoff, u.q);
        stc8(det_sw0 + eoff, 0ull);
        *(f32x4*)(det_fp0 + blk * 1024 + tid * 4) = (f32x4){0.f, 0.f, 0.f, 0.f};
    }
    if (tid < 128) {   // swizzle obs(:, t=0, :) — row blk
        int g = tid;
        const float* src = obs + (size_t)blk * T_ * 1024 + g * 8;
        bfrag v;
#pragma unroll
        for (int i = 0; i < 8; ++i) v[i] = (short)f2bf(src[i]);
        stc16b(obs_sw + ((size_t)g * 64 + blk) * 8, v);
    }
    gbar(barcnt, ep);

    ushort_t* dsw_in = det_sw0; ushort_t* dsw_out = det_sw1;
    float* dfp_in = det_fp0;    float* dfp_out = det_fp1;

#pragma unroll 1
    for (int t = 0; t < T_; ++t) {
        // ================= phase A: GRU =================
        {
            const int lane = tid & 63, w = tid >> 6;
            const int m = lane & 15, quad = lane >> 4;
            const int j0 = blk * 16;

            f32x4 acc[2][3][4];
#pragma unroll
            for (int a2 = 0; a2 < 2; ++a2)
#pragma unroll
                for (int g = 0; g < 3; ++g)
#pragma unroll
                    for (int n = 0; n < 4; ++n) acc[a2][g][n] = (f32x4){0.f, 0.f, 0.f, 0.f};

            const int kb0 = w * 256;
            const ushort_t* arow[2][3];
#pragma unroll
            for (int g = 0; g < 3; ++g) {
                arow[0][g] = Wih + (size_t)(g * 1024 + j0 + m) * 1024 + kb0 + quad * 8;
                arow[1][g] = Whh + (size_t)(g * 1024 + j0 + m) * 1024 + kb0 + quad * 8;
            }
            const ushort_t* bx = emb_sw + ((kb0 >> 3) + quad) * 512 + m * 8;
            const ushort_t* bh = dsw_in + ((kb0 >> 3) + quad) * 512 + m * 8;

#pragma unroll
            for (int it = 0; it < 8; ++it) {
                bfrag a[2][3], vx[4], vh[4];
#pragma unroll
                for (int g = 0; g < 3; ++g) {
                    a[0][g] = *(const bfrag*)(arow[0][g] + it * 32);
                    a[1][g] = *(const bfrag*)(arow[1][g] + it * 32);
                }
#pragma unroll
                for (int n = 0; n < 4; ++n) {
                    vx[n] = ldc16b(bx + it * 2048 + n * 128);
                    vh[n] = ldc16b(bh + it * 2048 + n * 128);
                }
#pragma unroll
                for (int g = 0; g < 3; ++g)
#pragma unroll
                    for (int n = 0; n < 4; ++n) {
                        acc[0][g][n] = __builtin_amdgcn_mfma_f32_16x16x32_bf16(a[0][g], vx[n], acc[0][g][n], 0, 0, 0);
                        acc[1][g][n] = __builtin_amdgcn_mfma_f32_16x16x32_bf16(a[1][g], vh[n], acc[1][g][n], 0, 0, 0);
                    }
            }

            // two-phase cross-wave reduction (waves 1,3 dump; waves 0,2 add)
            if (w & 1) {
                float* dst = red + (w >> 1) * 6144;
#pragma unroll
                for (int a2 = 0; a2 < 2; ++a2)
#pragma unroll
                    for (int g = 0; g < 3; ++g)
#pragma unroll
                        for (int n = 0; n < 4; ++n)
                            *(f32x4*)(dst + ((a2 * 3 + g) * 4 + n) * 256 + lane * 4) = acc[a2][g][n];
            }
            __syncthreads();
            if (!(w & 1)) {
                float* dst = red + (w >> 1) * 6144;
#pragma unroll
                for (int a2 = 0; a2 < 2; ++a2)
#pragma unroll
                    for (int g = 0; g < 3; ++g)
#pragma unroll
                        for (int n = 0; n < 4; ++n) {
                            float* pp = dst + ((a2 * 3 + g) * 4 + n) * 256 + lane * 4;
                            f32x4 v = *(const f32x4*)pp;
                            v += acc[a2][g][n];
                            *(f32x4*)pp = v;
                        }
            }
            __syncthreads();

            // gate phase: thread -> (b = tid>>2, jq = tid&3)
            int b = tid >> 2, jq = tid & 3;
            int nt = b >> 4, bl = b & 15;
            int lsrc = (jq * 16 + bl) * 4;
            float gg[2][3][4];
#pragma unroll
            for (int a2 = 0; a2 < 2; ++a2)
#pragma unroll
                for (int g = 0; g < 3; ++g) {
                    f32x4 v0 = *(const f32x4*)(red + ((a2 * 3 + g) * 4 + nt) * 256 + lsrc);
                    f32x4 v1 = *(const f32x4*)(red + 6144 + ((a2 * 3 + g) * 4 + nt) * 256 + lsrc);
#pragma unroll
                    for (int i = 0; i < 4; ++i) gg[a2][g][i] = v0[i] + v1[i];
                }
            f32x4 bi[3], bh2[3];
#pragma unroll
            for (int g = 0; g < 3; ++g) {
                bi[g] = *(const f32x4*)(bih + g * 1024 + j0 + jq * 4);
                bh2[g] = *(const f32x4*)(bhh + g * 1024 + j0 + jq * 4);
            }
            f32x4 h4;
            U8 dq;
#pragma unroll
            for (int i = 0; i < 4; ++i) {
                int j = j0 + jq * 4 + i;
                float r = sigmoidf_(gg[0][0][i] + bi[0][i] + gg[1][0][i] + bh2[0][i]);
                float z = sigmoidf_(gg[0][1][i] + bi[1][i] + gg[1][1][i] + bh2[1][i]);
                float n = tanhf(gg[0][2][i] + bi[2][i] + r * (gg[1][2][i] + bh2[2][i]));
                float hp = dfp_in[j * 64 + b];
                float h = (1.f - z) * n + z * hp;
                h4[i] = h;
                dq.v4[i] = f2bf(h);
                dfp_out[j * 64 + b] = h;
            }
            *(f32x4*)(out + ((size_t)b * T_ + t) * OUTD + j0 + jq * 4) = h4;
            int kbase = j0 + jq * 4;
            stc8(dsw_out + ((size_t)(kbase >> 3) * 64 + b) * 8 + (kbase & 7), dq.q);
        }
        gbar(barcnt, ep);

        // ================= phase B: pm1 / qm1 =================
        {
            const int lane = tid & 63, w = tid >> 6;
            const int m = lane & 15, quad = lane >> 4;
            const bool isq = blk >= 32;
            const int j0 = (isq ? blk - 32 : blk) * 16;

            f32x4 acc[4];
#pragma unroll
            for (int n = 0; n < 4; ++n) acc[n] = (f32x4){0.f, 0.f, 0.f, 0.f};

            if (!isq) {
                const ushort_t* ar = Wp1b + (size_t)(j0 + m) * 1024 + w * 256 + quad * 8;
                const ushort_t* bb = dsw_out + ((w * 32) + quad) * 512 + m * 8;
#pragma unroll
                for (int it = 0; it < 8; ++it) {
                    bfrag a = *(const bfrag*)(ar + it * 32);
#pragma unroll
                    for (int n = 0; n < 4; ++n) {
                        bfrag v = ldc16b(bb + it * 2048 + n * 128);
                        acc[n] = __builtin_amdgcn_mfma_f32_16x16x32_bf16(a, v, acc[n], 0, 0, 0);
                    }
                }
            } else {
                int kb0 = w * 512;
                const ushort_t* bsrc = (w < 2) ? dsw_out : obs_sw;
                int kloc = (w < 2) ? kb0 : kb0 - 1024;
                const ushort_t* ar = Wq1b + (size_t)(j0 + m) * 2048 + kb0 + quad * 8;
                const ushort_t* bb = bsrc + ((kloc >> 3) + quad) * 512 + m * 8;
#pragma unroll
                for (int it = 0; it < 16; ++it) {
                    bfrag a = *(const bfrag*)(ar + it * 32);
#pragma unroll
                    for (int n = 0; n < 4; ++n) {
                        bfrag v = ldc16b(bb + it * 2048 + n * 128);
                        acc[n] = __builtin_amdgcn_mfma_f32_16x16x32_bf16(a, v, acc[n], 0, 0, 0);
                    }
                }
            }
#pragma unroll
            for (int n = 0; n < 4; ++n)
                *(f32x4*)(red + (w * 4 + n) * 256 + lane * 4) = acc[n];
            __syncthreads();

            int b = tid >> 2, jq = tid & 3;
            int nt = b >> 4, lsrc = (jq * 16 + (b & 15)) * 4;
            f32x4 s = (f32x4){0.f, 0.f, 0.f, 0.f};
#pragma unroll
            for (int w2 = 0; w2 < 4; ++w2) s += *(const f32x4*)(red + (w2 * 4 + nt) * 256 + lsrc);
            f32x4 bv = *(const f32x4*)((isq ? bq1 : bp1) + j0 + jq * 4);
            f32x4 r;
#pragma unroll
            for (int i = 0; i < 4; ++i) r[i] = fmaxf(s[i] + bv[i], 0.f);
            stc16f((isq ? qm1 : pm1) + (size_t)b * 512 + j0 + jq * 4, r);
        }
        gbar(barcnt, ep);

        // ================= phase C: heads + stats + emb(t+1) + obs(t+1) =====
        {
            float* s_p = red;
            float* s_q = red + 512;
            float* s_head = red + 1024;
            float* s_in = red + 1152;   // [0,32) stoch, [32,96) act(t+1)
            const int b = blk;
            if (tid < 128) ((f32x4*)s_p)[tid] = ldc16f(pm1 + (size_t)b * 512 + tid * 4);
            else ((f32x4*)s_q)[tid - 128] = ldc16f(qm1 + (size_t)b * 512 + (tid - 128) * 4);
            if (t + 1 < T_ && tid < 64) s_in[32 + tid] = act[((size_t)b * T_ + t + 1) * 64 + tid];
            if (t + 1 < T_ && tid >= 128) {   // swizzle obs(:, t+1, :) row b
                int g = tid - 128;            // [0,128) — ONE k-group per thread
                const float* src0 = obs + ((size_t)b * T_ + t + 1) * 1024 + g * 8;
                bfrag v0;
#pragma unroll
                for (int i = 0; i < 8; ++i) v0[i] = (short)f2bf(src0[i]);
                stc16b(obs_sw + ((size_t)g * 64 + b) * 8, v0);
            }
            __syncthreads();
            if (tid < 128) {
                int head = tid >> 6, o = tid & 63;
                const ushort_t* wp = W2sw + head * 32768 + o * 8;
                const float* hv = head ? s_q : s_p;
                float acc2 = (head ? bq2 : bp2)[o];
#pragma unroll 8
                for (int g = 0; g < 64; ++g) {
                    bfrag w8 = *(const bfrag*)(wp + g * 512);
#pragma unroll
                    for (int i2 = 0; i2 < 8; ++i2) acc2 += hv[g * 8 + i2] * bf2f((ushort_t)w8[i2]);
                }
                s_head[tid] = acc2;
            }
            __syncthreads();
            if (tid < 64) {
                int s = tid & 31, isq = tid >> 5;
                float mean = s_head[isq * 64 + s];
                float raw = s_head[isq * 64 + 32 + s];
                float sd = softplusf_(raw) + 1e-5f;
                float noise = (isq ? n_q : n_p)[((size_t)b * T_ + t) * 32 + s];
                float st = mean + sd * noise;
                float* o = out + ((size_t)b * T_ + t) * OUTD + 1024 + isq * 96;
                o[s] = mean;
                o[32 + s] = sd;
                o[64 + s] = st;
                if (isq) s_in[s] = st;
            }
            __syncthreads();
            if (t + 1 < T_) {
                // emb(t+1): 4 CONSECUTIVE j per thread -> one aligned 8B sc store
                int j0 = tid * 4;
                float acc4[4];
#pragma unroll
                for (int jj = 0; jj < 4; ++jj) acc4[jj] = bsa[j0 + jj];
#pragma unroll
                for (int g = 0; g < 12; ++g) {
#pragma unroll
                    for (int jj = 0; jj < 4; ++jj) {
                        bfrag w8 = *(const bfrag*)(Wsasw + ((size_t)g * 1024 + j0 + jj) * 8);
#pragma unroll
                        for (int i2 = 0; i2 < 8; ++i2) acc4[jj] += s_in[g * 8 + i2] * bf2f((ushort_t)w8[i2]);
                    }
                }
                U8 u;
#pragma unroll
                for (int jj = 0; jj < 4; ++jj) u.v4[jj] = f2bf(fmaxf(acc4[jj], 0.f));
                stc8(emb_sw + ((size_t)(j0 >> 3) * 64 + b) * 8 + (j0 & 7), u.q);
            }
        }
        gbar(barcnt, ep);

        // swap det ping-pong
        ushort_t* ts = dsw_in; dsw_in = dsw_out; dsw_out = ts;
        float* tf = dfp_in; dfp_in = dfp_out; dfp_out = tf;
    }
}

extern "C" void kernel_launch(void* const* d_in, const int* in_sizes, int n_in,
                              void* d_out, int out_size, void* d_ws, size_t ws_size,
                              hipStream_t stream) {
    const float* obs = (const float*)d_in[0];
    const float* act = (const float*)d_in[1];
    const float* n_p = (const float*)d_in[2];
    const float* n_q = (const float*)d_in[3];
    const float* W_sa = (const float*)d_in[4];
    const float* b_sa = (const float*)d_in[5];
    const float* W_ih = (const float*)d_in[6];
    const float* b_ih = (const float*)d_in[7];
    const float* W_hh = (const float*)d_in[8];
    const float* b_hh = (const float*)d_in[9];
    const float* Wp1 = (const float*)d_in[10];
    const float* bp1 = (const float*)d_in[11];
    const float* Wp2 = (const float*)d_in[12];
    const float* bp2 = (const float*)d_in[13];
    const float* Wq1 = (const float*)d_in[14];
    const float* bq1 = (const float*)d_in[15];
    const float* Wq2 = (const float*)d_in[16];
    const float* bq2 = (const float*)d_in[17];
    float* out = (float*)d_out;

    char* p = (char*)d_ws;
    ushort_t* Wih_b = (ushort_t*)p;  p += (size_t)3145728 * 2;
    ushort_t* Whh_b = (ushort_t*)p;  p += (size_t)3145728 * 2;
    ushort_t* Wp1_b = (ushort_t*)p;  p += (size_t)524288 * 2;
    ushort_t* Wq1_b = (ushort_t*)p;  p += (size_t)1048576 * 2;
    ushort_t* W2sw  = (ushort_t*)p;  p += (size_t)65536 * 2;
    ushort_t* Wsasw = (ushort_t*)p;  p += (size_t)98304 * 2;
    ushort_t* emb_sw = (ushort_t*)p; p += (size_t)65536 * 2;
    ushort_t* obs_sw = (ushort_t*)p; p += (size_t)65536 * 2;
    ushort_t* det_sw0 = (ushort_t*)p; p += (size_t)65536 * 2;
    ushort_t* det_sw1 = (ushort_t*)p; p += (size_t)65536 * 2;
    float* det_fp0 = (float*)p; p += (size_t)65536 * 4;
    float* det_fp1 = (float*)p; p += (size_t)65536 * 4;
    float* pm1 = (float*)p; p += (size_t)32768 * 4;
    float* qm1 = (float*)p; p += (size_t)32768 * 4;
    unsigned* barcnt = (unsigned*)p; p += 256;

    kwprep<<<1024, 256, 0, stream>>>(W_ih, W_hh, Wp1, Wq1, Wp2, Wq2, W_sa,
                                     Wih_b, Whh_b, Wp1_b, Wq1_b, W2sw, Wsasw, barcnt);
    krssm<<<NBLK, 256, 0, stream>>>(obs, act, n_p, n_q, W_sa, b_sa,
                                    Wih_b, Whh_b, b_ih, b_hh,
                                    Wp1_b, bp1, Wq1_b, bq1,
                                    W2sw, Wsasw, bp2, bq2,
                                    emb_sw, obs_sw, det_sw0, det_sw1,
                                    det_fp0, det_fp1, pm1, qm1, out, barcnt);
}

// Round 5
// 17436.852 us; speedup vs baseline: 1.3317x; 1.0402x over previous
//
#include <hip/hip_runtime.h>
#include <math.h>

#define B_   64
#define T_   256
#define OUTD 1216
#define NBLK 64

typedef unsigned short ushort_t;
typedef unsigned int   uint32;
typedef unsigned long long u64;
typedef __attribute__((ext_vector_type(8))) short bfrag;   // 8 bf16
typedef __attribute__((ext_vector_type(4))) float f32x4;
typedef __attribute__((ext_vector_type(4))) unsigned short us4;

#define SCOPE_AGT __HIP_MEMORY_SCOPE_AGENT

__device__ __forceinline__ float sigmoidf_(float x) { return 1.0f / (1.0f + __expf(-x)); }
__device__ __forceinline__ float softplusf_(float x) { return (x > 20.0f) ? x : log1pf(__expf(x)); }
__device__ __forceinline__ ushort_t f2bf(float f) {
    uint32 u = __float_as_uint(f);
    u += 0x7fffu + ((u >> 16) & 1u);
    return (ushort_t)(u >> 16);
}
__device__ __forceinline__ float bf2f(ushort_t u) { return __uint_as_float(((uint32)u) << 16); }

// ---------------------------------------------------------------------------
// Agent-coherent (cross-XCD) access helpers: RELAXED+AGENT atomics -> sc1
// loads/stores that go to the coherent point, bypassing the non-coherent
// per-XCD L2s. Used ONLY for the ~600KB/step of cross-block activations.
// ---------------------------------------------------------------------------
union U16 { u64 q[2]; bfrag bv; f32x4 fv; };
union U8  { u64 q; us4 v4; };

__device__ __forceinline__ u64 ldc8(const void* p) {
    return __hip_atomic_load((const u64*)p, __ATOMIC_RELAXED, SCOPE_AGT);
}
__device__ __forceinline__ void stc8(void* p, u64 v) {
    __hip_atomic_store((u64*)p, v, __ATOMIC_RELAXED, SCOPE_AGT);
}
__device__ __forceinline__ bfrag ldc16b(const void* p) {
    U16 u; u.q[0] = ldc8(p); u.q[1] = ldc8((const u64*)p + 1); return u.bv;
}
__device__ __forceinline__ f32x4 ldc16f(const void* p) {
    U16 u; u.q[0] = ldc8(p); u.q[1] = ldc8((const u64*)p + 1); return u.fv;
}
__device__ __forceinline__ void stc16f(void* p, f32x4 v) {
    U16 u; u.fv = v; stc8(p, u.q[0]); stc8((u64*)p + 1, u.q[1]);
}
__device__ __forceinline__ void stc16b(void* p, bfrag v) {
    U16 u; u.bv = v; stc8(p, u.q[0]); stc8((u64*)p + 1, u.q[1]);
}

// ---------------------------------------------------------------------------
// kwprep: one-time weight conversion (+ zero the barrier counter AND the
// 64 per-block flag lines so each graph replay starts clean).
// ---------------------------------------------------------------------------
__global__ void kwprep(const float* __restrict__ Wih, const float* __restrict__ Whh,
                       const float* __restrict__ Wp1, const float* __restrict__ Wq1,
                       const float* __restrict__ Wp2, const float* __restrict__ Wq2,
                       const float* __restrict__ Wsa,
                       ushort_t* Wih_b, ushort_t* Whh_b, ushort_t* Wp1_b, ushort_t* Wq1_b,
                       ushort_t* W2sw, ushort_t* Wsasw, unsigned* gsync) {
    int stride = gridDim.x * blockDim.x;
    int gid = blockIdx.x * blockDim.x + threadIdx.x;
    for (int i = gid; i < 4096; i += stride) gsync[i] = 0u;
    for (int i = gid; i < 3072 * 1024; i += stride) Wih_b[i] = f2bf(Wih[i]);
    for (int i = gid; i < 3072 * 1024; i += stride) Whh_b[i] = f2bf(Whh[i]);
    for (int i = gid; i < 512 * 1024; i += stride) Wp1_b[i] = f2bf(Wp1[i]);
    for (int i = gid; i < 512 * 2048; i += stride) Wq1_b[i] = f2bf(Wq1[i]);
    for (int i = gid; i < 65536; i += stride) {
        int head = i >> 15, g = (i >> 9) & 63, o = (i >> 3) & 63, ii = i & 7;
        const float* src = head ? Wq2 : Wp2;
        W2sw[i] = f2bf(src[o * 512 + g * 8 + ii]);
    }
    for (int i = gid; i < 98304; i += stride) {
        int g = i >> 13, j = (i >> 3) & 1023, ii = i & 7;
        Wsasw[i] = f2bf(Wsa[j * 96 + g * 8 + ii]);
    }
}

// ---------------------------------------------------------------------------
// Scalable grid barrier (distributed flags). gsync[0] = monotonic arrival
// counter (touched ONLY by 64 fetch_adds per epoch — nobody polls it).
// gsync[64 + blk*32] = per-block epoch flag, one 128B-spaced line per block,
// exactly ONE spinner per line. The last arriver publishes the epoch to all
// 64 flags. Previous design had 63 blocks polling ONE line with agent-scope
// atomic loads -> TCC atomic-queue saturation -> ~23 us/barrier floor
// (invariant across rounds 3/4's fence changes — the smoking gun).
// Data visibility: cross-block data is sc1-stored and drained by vmcnt(0)
// before the arrival add; readers use sc1 loads. No cache fences needed.
// ---------------------------------------------------------------------------
__device__ __forceinline__ void gbar(unsigned* gs, int blk, unsigned& ep) {
    asm volatile("s_waitcnt vmcnt(0)" ::: "memory");
    __syncthreads();
    ++ep;
    if (threadIdx.x == 0) {
        unsigned old = __hip_atomic_fetch_add(gs, 1u, __ATOMIC_RELAXED, SCOPE_AGT);
        if (old == ep * (unsigned)NBLK - 1u) {
            // last arriver: publish epoch to all 64 private flag lines
#pragma unroll 8
            for (int i = 0; i < NBLK; ++i)
                __hip_atomic_store(gs + 64 + i * 32, ep, __ATOMIC_RELAXED, SCOPE_AGT);
        } else {
            unsigned* f = gs + 64 + blk * 32;
            while (__hip_atomic_load(f, __ATOMIC_RELAXED, SCOPE_AGT) < ep)
                __builtin_amdgcn_s_sleep(8);
        }
    }
    __syncthreads();
}

// ---------------------------------------------------------------------------
// krssm: the whole T=256 rollout in ONE persistent kernel.
//   prologue: emb(0) (stoch0=0), zero det buffers, swizzle obs(:,0,:)
//   loop t:  A) GRU (this block's 16-j slice)        -> bar
//            B) pm1/qm1 hidden matmuls               -> bar
//            C) heads + stats + emb(t+1) + obs(t+1)  -> bar
// Cross-block arrays (sc1 path): emb_sw, det_sw0/1, obs_sw, pm1, qm1.
// Block-private (cached path): det_fp (same j-slice producer/consumer), out.
// ---------------------------------------------------------------------------
__global__ __launch_bounds__(256, 1) void krssm(
        const float* __restrict__ obs, const float* __restrict__ act,
        const float* __restrict__ n_p, const float* __restrict__ n_q,
        const float* __restrict__ Wsa, const float* __restrict__ bsa,
        const ushort_t* __restrict__ Wih, const ushort_t* __restrict__ Whh,
        const float* __restrict__ bih, const float* __restrict__ bhh,
        const ushort_t* __restrict__ Wp1b, const float* __restrict__ bp1,
        const ushort_t* __restrict__ Wq1b, const float* __restrict__ bq1,
        const ushort_t* __restrict__ W2sw, const ushort_t* __restrict__ Wsasw,
        const float* __restrict__ bp2, const float* __restrict__ bq2,
        ushort_t* emb_sw, ushort_t* obs_sw,
        ushort_t* det_sw0, ushort_t* det_sw1, float* det_fp0, float* det_fp1,
        float* pm1, float* qm1, float* out, unsigned* gsync) {
    __shared__ float red[2 * 24 * 256];   // 48 KB, reused by all phases
    const int tid = threadIdx.x;
    const int blk = blockIdx.x;
    unsigned ep = 0;

    // ---- prologue: block blk owns batch row b=blk for emb(0)/obs(0);
    //      each thread covers 4 CONSECUTIVE j -> one aligned 8B sc store.
    //      det_fp0: zero OWN j-slice (block-private). ----
    {
        const int b = blk;
        const int j0 = tid * 4;
        const float* arow_ = act + (size_t)b * T_ * 64;
        float accp[4];
#pragma unroll
        for (int jj = 0; jj < 4; ++jj) {
            int j = j0 + jj;
            float acc = bsa[j];
            const float* w = Wsa + j * 96 + 32;
#pragma unroll 8
            for (int c = 0; c < 64; ++c) acc += arow_[c] * w[c];
            accp[jj] = fmaxf(acc, 0.f);
        }
        U8 u;
#pragma unroll
        for (int jj = 0; jj < 4; ++jj) u.v4[jj] = f2bf(accp[jj]);
        size_t eoff = ((size_t)(j0 >> 3) * 64 + b) * 8 + (j0 & 7);
        stc8(emb_sw + eoff, u.q);
        stc8(det_sw0 + eoff, 0ull);
        *(f32x4*)(det_fp0 + blk * 1024 + tid * 4) = (f32x4){0.f, 0.f, 0.f, 0.f};
    }
    if (tid < 128) {   // swizzle obs(:, t=0, :) — row blk
        int g = tid;
        const float* src = obs + (size_t)blk * T_ * 1024 + g * 8;
        bfrag v;
#pragma unroll
        for (int i = 0; i < 8; ++i) v[i] = (short)f2bf(src[i]);
        stc16b(obs_sw + ((size_t)g * 64 + blk) * 8, v);
    }
    gbar(gsync, blk, ep);

    ushort_t* dsw_in = det_sw0; ushort_t* dsw_out = det_sw1;
    float* dfp_in = det_fp0;    float* dfp_out = det_fp1;

#pragma unroll 1
    for (int t = 0; t < T_; ++t) {
        // ================= phase A: GRU =================
        {
            const int lane = tid & 63, w = tid >> 6;
            const int m = lane & 15, quad = lane >> 4;
            const int j0 = blk * 16;

            f32x4 acc[2][3][4];
#pragma unroll
            for (int a2 = 0; a2 < 2; ++a2)
#pragma unroll
                for (int g = 0; g < 3; ++g)
#pragma unroll
                    for (int n = 0; n < 4; ++n) acc[a2][g][n] = (f32x4){0.f, 0.f, 0.f, 0.f};

            const int kb0 = w * 256;
            const ushort_t* arow[2][3];
#pragma unroll
            for (int g = 0; g < 3; ++g) {
                arow[0][g] = Wih + (size_t)(g * 1024 + j0 + m) * 1024 + kb0 + quad * 8;
                arow[1][g] = Whh + (size_t)(g * 1024 + j0 + m) * 1024 + kb0 + quad * 8;
            }
            const ushort_t* bx = emb_sw + ((kb0 >> 3) + quad) * 512 + m * 8;
            const ushort_t* bh = dsw_in + ((kb0 >> 3) + quad) * 512 + m * 8;

#pragma unroll
            for (int it = 0; it < 8; ++it) {
                bfrag a[2][3], vx[4], vh[4];
#pragma unroll
                for (int g = 0; g < 3; ++g) {
                    a[0][g] = *(const bfrag*)(arow[0][g] + it * 32);
                    a[1][g] = *(const bfrag*)(arow[1][g] + it * 32);
                }
#pragma unroll
                for (int n = 0; n < 4; ++n) {
                    vx[n] = ldc16b(bx + it * 2048 + n * 128);
                    vh[n] = ldc16b(bh + it * 2048 + n * 128);
                }
#pragma unroll
                for (int g = 0; g < 3; ++g)
#pragma unroll
                    for (int n = 0; n < 4; ++n) {
                        acc[0][g][n] = __builtin_amdgcn_mfma_f32_16x16x32_bf16(a[0][g], vx[n], acc[0][g][n], 0, 0, 0);
                        acc[1][g][n] = __builtin_amdgcn_mfma_f32_16x16x32_bf16(a[1][g], vh[n], acc[1][g][n], 0, 0, 0);
                    }
            }

            // two-phase cross-wave reduction (waves 1,3 dump; waves 0,2 add)
            if (w & 1) {
                float* dst = red + (w >> 1) * 6144;
#pragma unroll
                for (int a2 = 0; a2 < 2; ++a2)
#pragma unroll
                    for (int g = 0; g < 3; ++g)
#pragma unroll
                        for (int n = 0; n < 4; ++n)
                            *(f32x4*)(dst + ((a2 * 3 + g) * 4 + n) * 256 + lane * 4) = acc[a2][g][n];
            }
            __syncthreads();
            if (!(w & 1)) {
                float* dst = red + (w >> 1) * 6144;
#pragma unroll
                for (int a2 = 0; a2 < 2; ++a2)
#pragma unroll
                    for (int g = 0; g < 3; ++g)
#pragma unroll
                        for (int n = 0; n < 4; ++n) {
                            float* pp = dst + ((a2 * 3 + g) * 4 + n) * 256 + lane * 4;
                            f32x4 v = *(const f32x4*)pp;
                            v += acc[a2][g][n];
                            *(f32x4*)pp = v;
                        }
            }
            __syncthreads();

            // gate phase: thread -> (b = tid>>2, jq = tid&3)
            int b = tid >> 2, jq = tid & 3;
            int nt = b >> 4, bl = b & 15;
            int lsrc = (jq * 16 + bl) * 4;
            float gg[2][3][4];
#pragma unroll
            for (int a2 = 0; a2 < 2; ++a2)
#pragma unroll
                for (int g = 0; g < 3; ++g) {
                    f32x4 v0 = *(const f32x4*)(red + ((a2 * 3 + g) * 4 + nt) * 256 + lsrc);
                    f32x4 v1 = *(const f32x4*)(red + 6144 + ((a2 * 3 + g) * 4 + nt) * 256 + lsrc);
#pragma unroll
                    for (int i = 0; i < 4; ++i) gg[a2][g][i] = v0[i] + v1[i];
                }
            f32x4 bi[3], bh2[3];
#pragma unroll
            for (int g = 0; g < 3; ++g) {
                bi[g] = *(const f32x4*)(bih + g * 1024 + j0 + jq * 4);
                bh2[g] = *(const f32x4*)(bhh + g * 1024 + j0 + jq * 4);
            }
            f32x4 h4;
            U8 dq;
#pragma unroll
            for (int i = 0; i < 4; ++i) {
                int j = j0 + jq * 4 + i;
                float r = sigmoidf_(gg[0][0][i] + bi[0][i] + gg[1][0][i] + bh2[0][i]);
                float z = sigmoidf_(gg[0][1][i] + bi[1][i] + gg[1][1][i] + bh2[1][i]);
                float n = tanhf(gg[0][2][i] + bi[2][i] + r * (gg[1][2][i] + bh2[2][i]));
                float hp = dfp_in[j * 64 + b];
                float h = (1.f - z) * n + z * hp;
                h4[i] = h;
                dq.v4[i] = f2bf(h);
                dfp_out[j * 64 + b] = h;
            }
            *(f32x4*)(out + ((size_t)b * T_ + t) * OUTD + j0 + jq * 4) = h4;
            int kbase = j0 + jq * 4;
            stc8(dsw_out + ((size_t)(kbase >> 3) * 64 + b) * 8 + (kbase & 7), dq.q);
        }
        gbar(gsync, blk, ep);

        // ================= phase B: pm1 / qm1 =================
        {
            const int lane = tid & 63, w = tid >> 6;
            const int m = lane & 15, quad = lane >> 4;
            const bool isq = blk >= 32;
            const int j0 = (isq ? blk - 32 : blk) * 16;

            f32x4 acc[4];
#pragma unroll
            for (int n = 0; n < 4; ++n) acc[n] = (f32x4){0.f, 0.f, 0.f, 0.f};

            if (!isq) {
                const ushort_t* ar = Wp1b + (size_t)(j0 + m) * 1024 + w * 256 + quad * 8;
                const ushort_t* bb = dsw_out + ((w * 32) + quad) * 512 + m * 8;
#pragma unroll
                for (int it = 0; it < 8; ++it) {
                    bfrag a = *(const bfrag*)(ar + it * 32);
#pragma unroll
                    for (int n = 0; n < 4; ++n) {
                        bfrag v = ldc16b(bb + it * 2048 + n * 128);
                        acc[n] = __builtin_amdgcn_mfma_f32_16x16x32_bf16(a, v, acc[n], 0, 0, 0);
                    }
                }
            } else {
                int kb0 = w * 512;
                const ushort_t* bsrc = (w < 2) ? dsw_out : obs_sw;
                int kloc = (w < 2) ? kb0 : kb0 - 1024;
                const ushort_t* ar = Wq1b + (size_t)(j0 + m) * 2048 + kb0 + quad * 8;
                const ushort_t* bb = bsrc + ((kloc >> 3) + quad) * 512 + m * 8;
#pragma unroll
                for (int it = 0; it < 16; ++it) {
                    bfrag a = *(const bfrag*)(ar + it * 32);
#pragma unroll
                    for (int n = 0; n < 4; ++n) {
                        bfrag v = ldc16b(bb + it * 2048 + n * 128);
                        acc[n] = __builtin_amdgcn_mfma_f32_16x16x32_bf16(a, v, acc[n], 0, 0, 0);
                    }
                }
            }
#pragma unroll
            for (int n = 0; n < 4; ++n)
                *(f32x4*)(red + (w * 4 + n) * 256 + lane * 4) = acc[n];
            __syncthreads();

            int b = tid >> 2, jq = tid & 3;
            int nt = b >> 4, lsrc = (jq * 16 + (b & 15)) * 4;
            f32x4 s = (f32x4){0.f, 0.f, 0.f, 0.f};
#pragma unroll
            for (int w2 = 0; w2 < 4; ++w2) s += *(const f32x4*)(red + (w2 * 4 + nt) * 256 + lsrc);
            f32x4 bv = *(const f32x4*)((isq ? bq1 : bp1) + j0 + jq * 4);
            f32x4 r;
#pragma unroll
            for (int i = 0; i < 4; ++i) r[i] = fmaxf(s[i] + bv[i], 0.f);
            stc16f((isq ? qm1 : pm1) + (size_t)b * 512 + j0 + jq * 4, r);
        }
        gbar(gsync, blk, ep);

        // ================= phase C: heads + stats + emb(t+1) + obs(t+1) =====
        {
            float* s_p = red;
            float* s_q = red + 512;
            float* s_head = red + 1024;
            float* s_in = red + 1152;   // [0,32) stoch, [32,96) act(t+1)
            const int b = blk;
            if (tid < 128) ((f32x4*)s_p)[tid] = ldc16f(pm1 + (size_t)b * 512 + tid * 4);
            else ((f32x4*)s_q)[tid - 128] = ldc16f(qm1 + (size_t)b * 512 + (tid - 128) * 4);
            if (t + 1 < T_ && tid < 64) s_in[32 + tid] = act[((size_t)b * T_ + t + 1) * 64 + tid];
            if (t + 1 < T_ && tid >= 128) {   // swizzle obs(:, t+1, :) row b
                int g = tid - 128;            // [0,128) — ONE k-group per thread
                const float* src0 = obs + ((size_t)b * T_ + t + 1) * 1024 + g * 8;
                bfrag v0;
#pragma unroll
                for (int i = 0; i < 8; ++i) v0[i] = (short)f2bf(src0[i]);
                stc16b(obs_sw + ((size_t)g * 64 + b) * 8, v0);
            }
            __syncthreads();
            if (tid < 128) {
                int head = tid >> 6, o = tid & 63;
                const ushort_t* wp = W2sw + head * 32768 + o * 8;
                const float* hv = head ? s_q : s_p;
                float acc2 = (head ? bq2 : bp2)[o];
#pragma unroll 8
                for (int g = 0; g < 64; ++g) {
                    bfrag w8 = *(const bfrag*)(wp + g * 512);
#pragma unroll
                    for (int i2 = 0; i2 < 8; ++i2) acc2 += hv[g * 8 + i2] * bf2f((ushort_t)w8[i2]);
                }
                s_head[tid] = acc2;
            }
            __syncthreads();
            if (tid < 64) {
                int s = tid & 31, isq = tid >> 5;
                float mean = s_head[isq * 64 + s];
                float raw = s_head[isq * 64 + 32 + s];
                float sd = softplusf_(raw) + 1e-5f;
                float noise = (isq ? n_q : n_p)[((size_t)b * T_ + t) * 32 + s];
                float st = mean + sd * noise;
                float* o = out + ((size_t)b * T_ + t) * OUTD + 1024 + isq * 96;
                o[s] = mean;
                o[32 + s] = sd;
                o[64 + s] = st;
                if (isq) s_in[s] = st;
            }
            __syncthreads();
            if (t + 1 < T_) {
                // emb(t+1): 4 CONSECUTIVE j per thread -> one aligned 8B sc store
                int j0 = tid * 4;
                float acc4[4];
#pragma unroll
                for (int jj = 0; jj < 4; ++jj) acc4[jj] = bsa[j0 + jj];
#pragma unroll
                for (int g = 0; g < 12; ++g) {
#pragma unroll
                    for (int jj = 0; jj < 4; ++jj) {
                        bfrag w8 = *(const bfrag*)(Wsasw + ((size_t)g * 1024 + j0 + jj) * 8);
#pragma unroll
                        for (int i2 = 0; i2 < 8; ++i2) acc4[jj] += s_in[g * 8 + i2] * bf2f((ushort_t)w8[i2]);
                    }
                }
                U8 u;
#pragma unroll
                for (int jj = 0; jj < 4; ++jj) u.v4[jj] = f2bf(fmaxf(acc4[jj], 0.f));
                stc8(emb_sw + ((size_t)(j0 >> 3) * 64 + b) * 8 + (j0 & 7), u.q);
            }
        }
        gbar(gsync, blk, ep);

        // swap det ping-pong
        ushort_t* ts = dsw_in; dsw_in = dsw_out; dsw_out = ts;
        float* tf = dfp_in; dfp_in = dfp_out; dfp_out = tf;
    }
}

extern "C" void kernel_launch(void* const* d_in, const int* in_sizes, int n_in,
                              void* d_out, int out_size, void* d_ws, size_t ws_size,
                              hipStream_t stream) {
    const float* obs = (const float*)d_in[0];
    const float* act = (const float*)d_in[1];
    const float* n_p = (const float*)d_in[2];
    const float* n_q = (const float*)d_in[3];
    const float* W_sa = (const float*)d_in[4];
    const float* b_sa = (const float*)d_in[5];
    const float* W_ih = (const float*)d_in[6];
    const float* b_ih = (const float*)d_in[7];
    const float* W_hh = (const float*)d_in[8];
    const float* b_hh = (const float*)d_in[9];
    const float* Wp1 = (const float*)d_in[10];
    const float* bp1 = (const float*)d_in[11];
    const float* Wp2 = (const float*)d_in[12];
    const float* bp2 = (const float*)d_in[13];
    const float* Wq1 = (const float*)d_in[14];
    const float* bq1 = (const float*)d_in[15];
    const float* Wq2 = (const float*)d_in[16];
    const float* bq2 = (const float*)d_in[17];
    float* out = (float*)d_out;

    char* p = (char*)d_ws;
    ushort_t* Wih_b = (ushort_t*)p;  p += (size_t)3145728 * 2;
    ushort_t* Whh_b = (ushort_t*)p;  p += (size_t)3145728 * 2;
    ushort_t* Wp1_b = (ushort_t*)p;  p += (size_t)524288 * 2;
    ushort_t* Wq1_b = (ushort_t*)p;  p += (size_t)1048576 * 2;
    ushort_t* W2sw  = (ushort_t*)p;  p += (size_t)65536 * 2;
    ushort_t* Wsasw = (ushort_t*)p;  p += (size_t)98304 * 2;
    ushort_t* emb_sw = (ushort_t*)p; p += (size_t)65536 * 2;
    ushort_t* obs_sw = (ushort_t*)p; p += (size_t)65536 * 2;
    ushort_t* det_sw0 = (ushort_t*)p; p += (size_t)65536 * 2;
    ushort_t* det_sw1 = (ushort_t*)p; p += (size_t)65536 * 2;
    float* det_fp0 = (float*)p; p += (size_t)65536 * 4;
    float* det_fp1 = (float*)p; p += (size_t)65536 * 4;
    float* pm1 = (float*)p; p += (size_t)32768 * 4;
    float* qm1 = (float*)p; p += (size_t)32768 * 4;
    unsigned* gsync = (unsigned*)p; p += 16384;   // [0]=counter, flags at +64, stride 32 u32

    kwprep<<<1024, 256, 0, stream>>>(W_ih, W_hh, Wp1, Wq1, Wp2, Wq2, W_sa,
                                     Wih_b, Whh_b, Wp1_b, Wq1_b, W2sw, Wsasw, gsync);
    krssm<<<NBLK, 256, 0, stream>>>(obs, act, n_p, n_q, W_sa, b_sa,
                                    Wih_b, Whh_b, b_ih, b_hh,
                                    Wp1_b, bp1, Wq1_b, bq1,
                                    W2sw, Wsasw, bp2, bq2,
                                    emb_sw, obs_sw, det_sw0, det_sw1,
                                    det_fp0, det_fp1, pm1, qm1, out, gsync);
}

// Round 6
// 13833.046 us; speedup vs baseline: 1.6786x; 1.2605x over previous
//
#include <hip/hip_runtime.h>
#include <math.h>

#define B_   64
#define T_   256
#define OUTD 1216
#define NBLK 64

typedef unsigned short ushort_t;
typedef unsigned int   uint32;
typedef unsigned long long u64;
typedef __attribute__((ext_vector_type(8))) short bfrag;   // 8 bf16
typedef __attribute__((ext_vector_type(4))) float f32x4;
typedef __attribute__((ext_vector_type(4))) unsigned short us4;

#define SCOPE_AGT __HIP_MEMORY_SCOPE_AGENT

__device__ __forceinline__ float sigmoidf_(float x) { return 1.0f / (1.0f + __expf(-x)); }
__device__ __forceinline__ float softplusf_(float x) { return (x > 20.0f) ? x : log1pf(__expf(x)); }
__device__ __forceinline__ ushort_t f2bf(float f) {
    uint32 u = __float_as_uint(f);
    u += 0x7fffu + ((u >> 16) & 1u);
    return (ushort_t)(u >> 16);
}
__device__ __forceinline__ float bf2f(ushort_t u) { return __uint_as_float(((uint32)u) << 16); }

// ---------------------------------------------------------------------------
// Coherence scheme (round 6): "write-through + rename".
//  - Cross-block activations are TIME-INDEXED (emb_sw[t], det_sw[t],
//    obs_sw[t]) so no address is ever re-written within a dispatch.
//  - Writers use sc1 (agent-scope relaxed atomic) stores -> data lands at the
//    coherent point. ~400KB/step total, fire-and-forget.
//  - Readers use PLAIN CACHED loads: the address is fresh, so no XCD L2 can
//    hold a stale line; the miss fills from the coherent point and the fill
//    is SHARED by all blocks on that XCD (hardware broadcast tree).
//  - Weights never get invalidated -> L2-resident for the whole rollout.
//  - Only pm1/qm1 (4KB/block/step) stay on the sc1 read path.
//  Rounds 3/4/5 showed: per-barrier cache fences (L2-cold phases) and sc1
//  bulk reads (L2-bypass, 8B, ~0.8TB/s effective) both cost ~20us/phase.
//  Cross-replay staleness is handled by the dispatch-boundary acquire.
// ---------------------------------------------------------------------------
union U16 { u64 q[2]; bfrag bv; f32x4 fv; };
union U8  { u64 q; us4 v4; };

__device__ __forceinline__ u64 ldc8(const void* p) {
    return __hip_atomic_load((const u64*)p, __ATOMIC_RELAXED, SCOPE_AGT);
}
__device__ __forceinline__ void stc8(void* p, u64 v) {
    __hip_atomic_store((u64*)p, v, __ATOMIC_RELAXED, SCOPE_AGT);
}
__device__ __forceinline__ f32x4 ldc16f(const void* p) {
    U16 u; u.q[0] = ldc8(p); u.q[1] = ldc8((const u64*)p + 1); return u.fv;
}
__device__ __forceinline__ void stc16f(void* p, f32x4 v) {
    U16 u; u.fv = v; stc8(p, u.q[0]); stc8((u64*)p + 1, u.q[1]);
}
__device__ __forceinline__ void stc16b(void* p, bfrag v) {
    U16 u; u.bv = v; stc8(p, u.q[0]); stc8((u64*)p + 1, u.q[1]);
}

// ---------------------------------------------------------------------------
// kwprep: one-time weight conversion (+ zero the gsync area).
// ---------------------------------------------------------------------------
__global__ void kwprep(const float* __restrict__ Wih, const float* __restrict__ Whh,
                       const float* __restrict__ Wp1, const float* __restrict__ Wq1,
                       const float* __restrict__ Wp2, const float* __restrict__ Wq2,
                       const float* __restrict__ Wsa,
                       ushort_t* Wih_b, ushort_t* Whh_b, ushort_t* Wp1_b, ushort_t* Wq1_b,
                       ushort_t* W2sw, ushort_t* Wsasw, unsigned* gsync) {
    int stride = gridDim.x * blockDim.x;
    int gid = blockIdx.x * blockDim.x + threadIdx.x;
    for (int i = gid; i < 4096; i += stride) gsync[i] = 0u;
    for (int i = gid; i < 3072 * 1024; i += stride) Wih_b[i] = f2bf(Wih[i]);
    for (int i = gid; i < 3072 * 1024; i += stride) Whh_b[i] = f2bf(Whh[i]);
    for (int i = gid; i < 512 * 1024; i += stride) Wp1_b[i] = f2bf(Wp1[i]);
    for (int i = gid; i < 512 * 2048; i += stride) Wq1_b[i] = f2bf(Wq1[i]);
    for (int i = gid; i < 65536; i += stride) {
        int head = i >> 15, g = (i >> 9) & 63, o = (i >> 3) & 63, ii = i & 7;
        const float* src = head ? Wq2 : Wp2;
        W2sw[i] = f2bf(src[o * 512 + g * 8 + ii]);
    }
    for (int i = gid; i < 98304; i += stride) {
        int g = i >> 13, j = (i >> 3) & 1023, ii = i & 7;
        Wsasw[i] = f2bf(Wsa[j * 96 + g * 8 + ii]);
    }
}

// ---------------------------------------------------------------------------
// Scalable grid barrier (distributed flags, proven in round 5).
// gsync[0] = arrival counter (64 fetch_adds/epoch, nobody polls it);
// gsync[64+blk*32] = per-block flag line, one spinner per line; last arriver
// publishes the epoch to all 64 flags. vmcnt(0) drain before arrival ensures
// all sc1 stores are at the coherent point before the epoch is published.
// ---------------------------------------------------------------------------
__device__ __forceinline__ void gbar(unsigned* gs, int blk, unsigned& ep) {
    asm volatile("s_waitcnt vmcnt(0)" ::: "memory");
    __syncthreads();
    ++ep;
    if (threadIdx.x == 0) {
        unsigned old = __hip_atomic_fetch_add(gs, 1u, __ATOMIC_RELAXED, SCOPE_AGT);
        if (old == ep * (unsigned)NBLK - 1u) {
#pragma unroll 8
            for (int i = 0; i < NBLK; ++i)
                __hip_atomic_store(gs + 64 + i * 32, ep, __ATOMIC_RELAXED, SCOPE_AGT);
        } else {
            unsigned* f = gs + 64 + blk * 32;
            while (__hip_atomic_load(f, __ATOMIC_RELAXED, SCOPE_AGT) < ep)
                __builtin_amdgcn_s_sleep(8);
        }
    }
    __syncthreads();
}

// ---------------------------------------------------------------------------
// krssm: whole T=256 rollout, one persistent kernel, 3 barriers/step.
//   A) GRU (block owns 16 j)  B) pm1/qm1  C) heads + stats + emb/obs(t+1)
// ---------------------------------------------------------------------------
__global__ __launch_bounds__(256, 1) void krssm(
        const float* __restrict__ obs, const float* __restrict__ act,
        const float* __restrict__ n_p, const float* __restrict__ n_q,
        const float* __restrict__ Wsa, const float* __restrict__ bsa,
        const ushort_t* __restrict__ Wih, const ushort_t* __restrict__ Whh,
        const float* __restrict__ bih, const float* __restrict__ bhh,
        const ushort_t* __restrict__ Wp1b, const float* __restrict__ bp1,
        const ushort_t* __restrict__ Wq1b, const float* __restrict__ bq1,
        const ushort_t* __restrict__ W2sw, const ushort_t* __restrict__ Wsasw,
        const float* __restrict__ bp2, const float* __restrict__ bq2,
        ushort_t* emb_sw, ushort_t* obs_sw, ushort_t* det_sw,
        float* det_fp0, float* det_fp1,
        float* pm1, float* qm1, float* out, unsigned* gsync) {
    __shared__ float red[2 * 24 * 256];   // 48 KB, reused by all phases
    const int tid = threadIdx.x;
    const int blk = blockIdx.x;
    unsigned ep = 0;

    // ---- prologue: emb_sw[0], det_sw[0]=0 (b=blk rows), obs_sw[0], det_fp0 ----
    {
        const int b = blk;
        const int j0 = tid * 4;
        const float* arow_ = act + (size_t)b * T_ * 64;
        float accp[4];
#pragma unroll
        for (int jj = 0; jj < 4; ++jj) {
            int j = j0 + jj;
            float acc = bsa[j];
            const float* w = Wsa + j * 96 + 32;
#pragma unroll 8
            for (int c = 0; c < 64; ++c) acc += arow_[c] * w[c];
            accp[jj] = fmaxf(acc, 0.f);
        }
        U8 u;
#pragma unroll
        for (int jj = 0; jj < 4; ++jj) u.v4[jj] = f2bf(accp[jj]);
        size_t eoff = ((size_t)(j0 >> 3) * 64 + b) * 8 + (j0 & 7);
        stc8(emb_sw + eoff, u.q);
        stc8(det_sw + eoff, 0ull);
        *(f32x4*)(det_fp0 + blk * 1024 + tid * 4) = (f32x4){0.f, 0.f, 0.f, 0.f};
    }
    if (tid < 128) {   // swizzle obs(:, t=0, :) — row blk
        int g = tid;
        const float* src = obs + (size_t)blk * T_ * 1024 + g * 8;
        bfrag v;
#pragma unroll
        for (int i = 0; i < 8; ++i) v[i] = (short)f2bf(src[i]);
        stc16b(obs_sw + ((size_t)g * 64 + blk) * 8, v);
    }
    gbar(gsync, blk, ep);

    float* dfp_in = det_fp0;
    float* dfp_out = det_fp1;

#pragma unroll 1
    for (int t = 0; t < T_; ++t) {
        const ushort_t* emb_t = emb_sw + ((size_t)t << 16);
        const ushort_t* det_t = det_sw + ((size_t)t << 16);
        ushort_t*       det_n = det_sw + ((size_t)(t + 1) << 16);
        const ushort_t* obs_t = obs_sw + ((size_t)t << 16);

        // ================= phase A: GRU =================
        {
            const int lane = tid & 63, w = tid >> 6;
            const int m = lane & 15, quad = lane >> 4;
            const int j0 = blk * 16;

            f32x4 acc[2][3][4];
#pragma unroll
            for (int a2 = 0; a2 < 2; ++a2)
#pragma unroll
                for (int g = 0; g < 3; ++g)
#pragma unroll
                    for (int n = 0; n < 4; ++n) acc[a2][g][n] = (f32x4){0.f, 0.f, 0.f, 0.f};

            const int kb0 = w * 256;
            const ushort_t* arow[2][3];
#pragma unroll
            for (int g = 0; g < 3; ++g) {
                arow[0][g] = Wih + (size_t)(g * 1024 + j0 + m) * 1024 + kb0 + quad * 8;
                arow[1][g] = Whh + (size_t)(g * 1024 + j0 + m) * 1024 + kb0 + quad * 8;
            }
            const ushort_t* bx = emb_t + ((kb0 >> 3) + quad) * 512 + m * 8;
            const ushort_t* bh = det_t + ((kb0 >> 3) + quad) * 512 + m * 8;

#pragma unroll
            for (int it = 0; it < 8; ++it) {
                bfrag a[2][3], vx[4], vh[4];
#pragma unroll
                for (int g = 0; g < 3; ++g) {
                    a[0][g] = *(const bfrag*)(arow[0][g] + it * 32);
                    a[1][g] = *(const bfrag*)(arow[1][g] + it * 32);
                }
#pragma unroll
                for (int n = 0; n < 4; ++n) {
                    vx[n] = *(const bfrag*)(bx + it * 2048 + n * 128);
                    vh[n] = *(const bfrag*)(bh + it * 2048 + n * 128);
                }
#pragma unroll
                for (int g = 0; g < 3; ++g)
#pragma unroll
                    for (int n = 0; n < 4; ++n) {
                        acc[0][g][n] = __builtin_amdgcn_mfma_f32_16x16x32_bf16(a[0][g], vx[n], acc[0][g][n], 0, 0, 0);
                        acc[1][g][n] = __builtin_amdgcn_mfma_f32_16x16x32_bf16(a[1][g], vh[n], acc[1][g][n], 0, 0, 0);
                    }
            }

            // two-phase cross-wave reduction (waves 1,3 dump; waves 0,2 add)
            if (w & 1) {
                float* dst = red + (w >> 1) * 6144;
#pragma unroll
                for (int a2 = 0; a2 < 2; ++a2)
#pragma unroll
                    for (int g = 0; g < 3; ++g)
#pragma unroll
                        for (int n = 0; n < 4; ++n)
                            *(f32x4*)(dst + ((a2 * 3 + g) * 4 + n) * 256 + lane * 4) = acc[a2][g][n];
            }
            __syncthreads();
            if (!(w & 1)) {
                float* dst = red + (w >> 1) * 6144;
#pragma unroll
                for (int a2 = 0; a2 < 2; ++a2)
#pragma unroll
                    for (int g = 0; g < 3; ++g)
#pragma unroll
                        for (int n = 0; n < 4; ++n) {
                            float* pp = dst + ((a2 * 3 + g) * 4 + n) * 256 + lane * 4;
                            f32x4 v = *(const f32x4*)pp;
                            v += acc[a2][g][n];
                            *(f32x4*)pp = v;
                        }
            }
            __syncthreads();

            // gate phase: thread -> (b = tid>>2, jq = tid&3)
            int b = tid >> 2, jq = tid & 3;
            int nt = b >> 4, bl = b & 15;
            int lsrc = (jq * 16 + bl) * 4;
            float gg[2][3][4];
#pragma unroll
            for (int a2 = 0; a2 < 2; ++a2)
#pragma unroll
                for (int g = 0; g < 3; ++g) {
                    f32x4 v0 = *(const f32x4*)(red + ((a2 * 3 + g) * 4 + nt) * 256 + lsrc);
                    f32x4 v1 = *(const f32x4*)(red + 6144 + ((a2 * 3 + g) * 4 + nt) * 256 + lsrc);
#pragma unroll
                    for (int i = 0; i < 4; ++i) gg[a2][g][i] = v0[i] + v1[i];
                }
            f32x4 bi[3], bh2[3];
#pragma unroll
            for (int g = 0; g < 3; ++g) {
                bi[g] = *(const f32x4*)(bih + g * 1024 + j0 + jq * 4);
                bh2[g] = *(const f32x4*)(bhh + g * 1024 + j0 + jq * 4);
            }
            f32x4 h4;
            U8 dq;
#pragma unroll
            for (int i = 0; i < 4; ++i) {
                int j = j0 + jq * 4 + i;
                float r = sigmoidf_(gg[0][0][i] + bi[0][i] + gg[1][0][i] + bh2[0][i]);
                float z = sigmoidf_(gg[0][1][i] + bi[1][i] + gg[1][1][i] + bh2[1][i]);
                float n = tanhf(gg[0][2][i] + bi[2][i] + r * (gg[1][2][i] + bh2[2][i]));
                float hp = dfp_in[j * 64 + b];
                float h = (1.f - z) * n + z * hp;
                h4[i] = h;
                dq.v4[i] = f2bf(h);
                dfp_out[j * 64 + b] = h;
            }
            *(f32x4*)(out + ((size_t)b * T_ + t) * OUTD + j0 + jq * 4) = h4;
            int kbase = j0 + jq * 4;
            stc8(det_n + ((size_t)(kbase >> 3) * 64 + b) * 8 + (kbase & 7), dq.q);
        }
        gbar(gsync, blk, ep);

        // ================= phase B: pm1 / qm1 =================
        {
            const int lane = tid & 63, w = tid >> 6;
            const int m = lane & 15, quad = lane >> 4;
            const bool isq = blk >= 32;
            const int j0 = (isq ? blk - 32 : blk) * 16;

            f32x4 acc[4];
#pragma unroll
            for (int n = 0; n < 4; ++n) acc[n] = (f32x4){0.f, 0.f, 0.f, 0.f};

            if (!isq) {
                const ushort_t* ar = Wp1b + (size_t)(j0 + m) * 1024 + w * 256 + quad * 8;
                const ushort_t* bb = det_n + ((w * 32) + quad) * 512 + m * 8;
#pragma unroll
                for (int it = 0; it < 8; ++it) {
                    bfrag a = *(const bfrag*)(ar + it * 32);
#pragma unroll
                    for (int n = 0; n < 4; ++n) {
                        bfrag v = *(const bfrag*)(bb + it * 2048 + n * 128);
                        acc[n] = __builtin_amdgcn_mfma_f32_16x16x32_bf16(a, v, acc[n], 0, 0, 0);
                    }
                }
            } else {
                int kb0 = w * 512;
                const ushort_t* bsrc = (w < 2) ? (const ushort_t*)det_n : obs_t;
                int kloc = (w < 2) ? kb0 : kb0 - 1024;
                const ushort_t* ar = Wq1b + (size_t)(j0 + m) * 2048 + kb0 + quad * 8;
                const ushort_t* bb = bsrc + ((kloc >> 3) + quad) * 512 + m * 8;
#pragma unroll
                for (int it = 0; it < 16; ++it) {
                    bfrag a = *(const bfrag*)(ar + it * 32);
#pragma unroll
                    for (int n = 0; n < 4; ++n) {
                        bfrag v = *(const bfrag*)(bb + it * 2048 + n * 128);
                        acc[n] = __builtin_amdgcn_mfma_f32_16x16x32_bf16(a, v, acc[n], 0, 0, 0);
                    }
                }
            }
#pragma unroll
            for (int n = 0; n < 4; ++n)
                *(f32x4*)(red + (w * 4 + n) * 256 + lane * 4) = acc[n];
            __syncthreads();

            int b = tid >> 2, jq = tid & 3;
            int nt = b >> 4, lsrc = (jq * 16 + (b & 15)) * 4;
            f32x4 s = (f32x4){0.f, 0.f, 0.f, 0.f};
#pragma unroll
            for (int w2 = 0; w2 < 4; ++w2) s += *(const f32x4*)(red + (w2 * 4 + nt) * 256 + lsrc);
            f32x4 bv = *(const f32x4*)((isq ? bq1 : bp1) + j0 + jq * 4);
            f32x4 r;
#pragma unroll
            for (int i = 0; i < 4; ++i) r[i] = fmaxf(s[i] + bv[i], 0.f);
            stc16f((isq ? qm1 : pm1) + (size_t)b * 512 + j0 + jq * 4, r);
        }
        gbar(gsync, blk, ep);

        // ================= phase C: heads + stats + emb(t+1) + obs(t+1) =====
        {
            float* s_p = red;
            float* s_q = red + 512;
            float* s_head = red + 1024;
            float* s_in = red + 1152;   // [0,32) stoch, [32,96) act(t+1)
            const int b = blk;
            if (tid < 128) ((f32x4*)s_p)[tid] = ldc16f(pm1 + (size_t)b * 512 + tid * 4);
            else ((f32x4*)s_q)[tid - 128] = ldc16f(qm1 + (size_t)b * 512 + (tid - 128) * 4);
            if (t + 1 < T_ && tid < 64) s_in[32 + tid] = act[((size_t)b * T_ + t + 1) * 64 + tid];
            if (t + 1 < T_ && tid >= 128) {   // swizzle obs(:, t+1, :) row b
                int g = tid - 128;            // [0,128) — ONE k-group per thread
                const float* src0 = obs + ((size_t)b * T_ + t + 1) * 1024 + g * 8;
                bfrag v0;
#pragma unroll
                for (int i = 0; i < 8; ++i) v0[i] = (short)f2bf(src0[i]);
                stc16b(obs_sw + ((size_t)(t + 1) << 16) + ((size_t)g * 64 + b) * 8, v0);
            }
            __syncthreads();
            if (tid < 128) {
                int head = tid >> 6, o = tid & 63;
                const ushort_t* wp = W2sw + head * 32768 + o * 8;
                const float* hv = head ? s_q : s_p;
                float acc2 = (head ? bq2 : bp2)[o];
#pragma unroll 8
                for (int g = 0; g < 64; ++g) {
                    bfrag w8 = *(const bfrag*)(wp + g * 512);
#pragma unroll
                    for (int i2 = 0; i2 < 8; ++i2) acc2 += hv[g * 8 + i2] * bf2f((ushort_t)w8[i2]);
                }
                s_head[tid] = acc2;
            }
            __syncthreads();
            if (tid < 64) {
                int s = tid & 31, isq = tid >> 5;
                float mean = s_head[isq * 64 + s];
                float raw = s_head[isq * 64 + 32 + s];
                float sd = softplusf_(raw) + 1e-5f;
                float noise = (isq ? n_q : n_p)[((size_t)b * T_ + t) * 32 + s];
                float st = mean + sd * noise;
                float* o = out + ((size_t)b * T_ + t) * OUTD + 1024 + isq * 96;
                o[s] = mean;
                o[32 + s] = sd;
                o[64 + s] = st;
                if (isq) s_in[s] = st;
            }
            __syncthreads();
            if (t + 1 < T_) {
                // emb(t+1): 4 CONSECUTIVE j per thread -> one aligned 8B sc store
                int j0 = tid * 4;
                float acc4[4];
#pragma unroll
                for (int jj = 0; jj < 4; ++jj) acc4[jj] = bsa[j0 + jj];
#pragma unroll
                for (int g = 0; g < 12; ++g) {
#pragma unroll
                    for (int jj = 0; jj < 4; ++jj) {
                        bfrag w8 = *(const bfrag*)(Wsasw + ((size_t)g * 1024 + j0 + jj) * 8);
#pragma unroll
                        for (int i2 = 0; i2 < 8; ++i2) acc4[jj] += s_in[g * 8 + i2] * bf2f((ushort_t)w8[i2]);
                    }
                }
                U8 u;
#pragma unroll
                for (int jj = 0; jj < 4; ++jj) u.v4[jj] = f2bf(fmaxf(acc4[jj], 0.f));
                stc8(emb_sw + ((size_t)(t + 1) << 16) + ((size_t)(j0 >> 3) * 64 + b) * 8 + (j0 & 7), u.q);
            }
        }
        gbar(gsync, blk, ep);

        // swap block-private det_fp ping-pong
        float* tf = dfp_in; dfp_in = dfp_out; dfp_out = tf;
    }
}

extern "C" void kernel_launch(void* const* d_in, const int* in_sizes, int n_in,
                              void* d_out, int out_size, void* d_ws, size_t ws_size,
                              hipStream_t stream) {
    const float* obs = (const float*)d_in[0];
    const float* act = (const float*)d_in[1];
    const float* n_p = (const float*)d_in[2];
    const float* n_q = (const float*)d_in[3];
    const float* W_sa = (const float*)d_in[4];
    const float* b_sa = (const float*)d_in[5];
    const float* W_ih = (const float*)d_in[6];
    const float* b_ih = (const float*)d_in[7];
    const float* W_hh = (const float*)d_in[8];
    const float* b_hh = (const float*)d_in[9];
    const float* Wp1 = (const float*)d_in[10];
    const float* bp1 = (const float*)d_in[11];
    const float* Wp2 = (const float*)d_in[12];
    const float* bp2 = (const float*)d_in[13];
    const float* Wq1 = (const float*)d_in[14];
    const float* bq1 = (const float*)d_in[15];
    const float* Wq2 = (const float*)d_in[16];
    const float* bq2 = (const float*)d_in[17];
    float* out = (float*)d_out;

    // workspace need: ~15.4MB weights + ~1.1MB small + 3 time-indexed
    // activation arrays (32 + 32 + 32.125 MB) ~= 113 MB
    if (ws_size < (size_t)115 * 1024 * 1024) return;

    char* p = (char*)d_ws;
    ushort_t* Wih_b = (ushort_t*)p;  p += (size_t)3145728 * 2;
    ushort_t* Whh_b = (ushort_t*)p;  p += (size_t)3145728 * 2;
    ushort_t* Wp1_b = (ushort_t*)p;  p += (size_t)524288 * 2;
    ushort_t* Wq1_b = (ushort_t*)p;  p += (size_t)1048576 * 2;
    ushort_t* W2sw  = (ushort_t*)p;  p += (size_t)65536 * 2;
    ushort_t* Wsasw = (ushort_t*)p;  p += (size_t)98304 * 2;
    float* pm1 = (float*)p; p += (size_t)32768 * 4;
    float* qm1 = (float*)p; p += (size_t)32768 * 4;
    float* det_fp0 = (float*)p; p += (size_t)65536 * 4;
    float* det_fp1 = (float*)p; p += (size_t)65536 * 4;
    unsigned* gsync = (unsigned*)p; p += (size_t)16384 * 4;
    ushort_t* emb_sw = (ushort_t*)p; p += (size_t)256 * 65536 * 2;   // [t][...]
    ushort_t* obs_sw = (ushort_t*)p; p += (size_t)256 * 65536 * 2;   // [t][...]
    ushort_t* det_sw = (ushort_t*)p; p += (size_t)257 * 65536 * 2;   // [t][...]

    kwprep<<<1024, 256, 0, stream>>>(W_ih, W_hh, Wp1, Wq1, Wp2, Wq2, W_sa,
                                     Wih_b, Whh_b, Wp1_b, Wq1_b, W2sw, Wsasw, gsync);
    krssm<<<NBLK, 256, 0, stream>>>(obs, act, n_p, n_q, W_sa, b_sa,
                                    Wih_b, Whh_b, b_ih, b_hh,
                                    Wp1_b, bp1, Wq1_b, bq1,
                                    W2sw, Wsasw, bp2, bq2,
                                    emb_sw, obs_sw, det_sw,
                                    det_fp0, det_fp1, pm1, qm1, out, gsync);
}

// Round 8
// 11822.842 us; speedup vs baseline: 1.9640x; 1.1700x over previous
//
#include <hip/hip_runtime.h>
#include <math.h>

#define B_   64
#define T_   256
#define OUTD 1216
#define NBLK 64

typedef unsigned short ushort_t;
typedef unsigned int   uint32;
typedef unsigned long long u64;
typedef __attribute__((ext_vector_type(8))) short bfrag;   // 8 bf16
typedef __attribute__((ext_vector_type(4))) float f32x4;
typedef __attribute__((ext_vector_type(4))) unsigned short us4;

#define SCOPE_AGT __HIP_MEMORY_SCOPE_AGENT

__device__ __forceinline__ float sigmoidf_(float x) { return 1.0f / (1.0f + __expf(-x)); }
__device__ __forceinline__ float softplusf_(float x) { return (x > 20.0f) ? x : log1pf(__expf(x)); }
__device__ __forceinline__ ushort_t f2bf(float f) {
    uint32 u = __float_as_uint(f);
    u += 0x7fffu + ((u >> 16) & 1u);
    return (ushort_t)(u >> 16);
}
__device__ __forceinline__ float bf2f(ushort_t u) { return __uint_as_float(((uint32)u) << 16); }

// ---------------------------------------------------------------------------
// Agent-coherent helpers (sc1 path): only for cross-block activation WRITES
// and the small pm1/qm1 reads. Bulk activation READS are plain cached loads
// on time-indexed (never-rewritten) addresses — round 6's scheme, kept.
// ---------------------------------------------------------------------------
union U16 { u64 q[2]; bfrag bv; f32x4 fv; };
union U8  { u64 q; us4 v4; };

__device__ __forceinline__ u64 ldc8(const void* p) {
    return __hip_atomic_load((const u64*)p, __ATOMIC_RELAXED, SCOPE_AGT);
}
__device__ __forceinline__ void stc8(void* p, u64 v) {
    __hip_atomic_store((u64*)p, v, __ATOMIC_RELAXED, SCOPE_AGT);
}
__device__ __forceinline__ f32x4 ldc16f(const void* p) {
    U16 u; u.q[0] = ldc8(p); u.q[1] = ldc8((const u64*)p + 1); return u.fv;
}
__device__ __forceinline__ void stc16f(void* p, f32x4 v) {
    U16 u; u.fv = v; stc8(p, u.q[0]); stc8((u64*)p + 1, u.q[1]);
}
__device__ __forceinline__ void stc16b(void* p, bfrag v) {
    U16 u; u.bv = v; stc8(p, u.q[0]); stc8((u64*)p + 1, u.q[1]);
}

// ---------------------------------------------------------------------------
// kwprep: one-time weight conversion (+ zero the gsync area).
// ---------------------------------------------------------------------------
__global__ void kwprep(const float* __restrict__ Wih, const float* __restrict__ Whh,
                       const float* __restrict__ Wp1, const float* __restrict__ Wq1,
                       const float* __restrict__ Wp2, const float* __restrict__ Wq2,
                       const float* __restrict__ Wsa,
                       ushort_t* Wih_b, ushort_t* Whh_b, ushort_t* Wp1_b, ushort_t* Wq1_b,
                       ushort_t* W2sw, ushort_t* Wsasw, unsigned* gsync) {
    int stride = gridDim.x * blockDim.x;
    int gid = blockIdx.x * blockDim.x + threadIdx.x;
    for (int i = gid; i < 4096; i += stride) gsync[i] = 0u;
    for (int i = gid; i < 3072 * 1024; i += stride) Wih_b[i] = f2bf(Wih[i]);
    for (int i = gid; i < 3072 * 1024; i += stride) Whh_b[i] = f2bf(Whh[i]);
    for (int i = gid; i < 512 * 1024; i += stride) Wp1_b[i] = f2bf(Wp1[i]);
    for (int i = gid; i < 512 * 2048; i += stride) Wq1_b[i] = f2bf(Wq1[i]);
    for (int i = gid; i < 65536; i += stride) {
        int head = i >> 15, g = (i >> 9) & 63, o = (i >> 3) & 63, ii = i & 7;
        const float* src = head ? Wq2 : Wp2;
        W2sw[i] = f2bf(src[o * 512 + g * 8 + ii]);
    }
    for (int i = gid; i < 98304; i += stride) {
        int g = i >> 13, j = (i >> 3) & 1023, ii = i & 7;
        Wsasw[i] = f2bf(Wsa[j * 96 + g * 8 + ii]);
    }
}

// ---------------------------------------------------------------------------
// Scalable grid barrier (distributed flags, rounds 5/6). s_sleep(1) for
// faster wake. Data visibility: sc1 stores drained by vmcnt(0) before the
// arrival add; readers use sc1 loads / fresh-address cached loads.
// ---------------------------------------------------------------------------
__device__ __forceinline__ void gbar(unsigned* gs, int blk, unsigned& ep) {
    asm volatile("s_waitcnt vmcnt(0)" ::: "memory");
    __syncthreads();
    ++ep;
    if (threadIdx.x == 0) {
        unsigned old = __hip_atomic_fetch_add(gs, 1u, __ATOMIC_RELAXED, SCOPE_AGT);
        if (old == ep * (unsigned)NBLK - 1u) {
#pragma unroll 8
            for (int i = 0; i < NBLK; ++i)
                __hip_atomic_store(gs + 64 + i * 32, ep, __ATOMIC_RELAXED, SCOPE_AGT);
        } else {
            unsigned* f = gs + 64 + blk * 32;
            while (__hip_atomic_load(f, __ATOMIC_RELAXED, SCOPE_AGT) < ep)
                __builtin_amdgcn_s_sleep(1);
        }
    }
    __syncthreads();
}

// ---------------------------------------------------------------------------
// krssm: whole rollout, 64 blocks x 512 threads (8 waves = 2/SIMD for TLP;
// round 6 ran 4 waves = 1/SIMD and every phase latency was serial-exposed).
// Wave decomposition: w = kw*2+bw; kw = K-quarter (as the old 4-wave split),
// bw = b-half (each wave covers 2 of the 4 n-blocks). LDS slab layout and
// gate/sum code are IDENTICAL to round 6 (same summation tree).
// ---------------------------------------------------------------------------
__global__ __launch_bounds__(512, 1) void krssm(
        const float* __restrict__ obs, const float* __restrict__ act,
        const float* __restrict__ n_p, const float* __restrict__ n_q,
        const float* __restrict__ Wsa, const float* __restrict__ bsa,
        const ushort_t* __restrict__ Wih, const ushort_t* __restrict__ Whh,
        const float* __restrict__ bih, const float* __restrict__ bhh,
        const ushort_t* __restrict__ Wp1b, const float* __restrict__ bp1,
        const ushort_t* __restrict__ Wq1b, const float* __restrict__ bq1,
        const ushort_t* __restrict__ W2sw, const ushort_t* __restrict__ Wsasw,
        const float* __restrict__ bp2, const float* __restrict__ bq2,
        ushort_t* emb_sw, ushort_t* obs_sw, ushort_t* det_sw,
        float* det_fp0, float* det_fp1,
        float* pm1, float* qm1, float* out, unsigned* gsync) {
    __shared__ float red[2 * 24 * 256];   // 48 KB, reused by all phases
    const int tid = threadIdx.x;
    const int blk = blockIdx.x;
    unsigned ep = 0;

    // ---- prologue ----
    if (tid < 256) {
        const int b = blk;
        const int j0 = tid * 4;
        const float* arow_ = act + (size_t)b * T_ * 64;
        float accp[4];
#pragma unroll
        for (int jj = 0; jj < 4; ++jj) {
            int j = j0 + jj;
            float acc = bsa[j];
            const float* w = Wsa + j * 96 + 32;
#pragma unroll 8
            for (int c = 0; c < 64; ++c) acc += arow_[c] * w[c];
            accp[jj] = fmaxf(acc, 0.f);
        }
        U8 u;
#pragma unroll
        for (int jj = 0; jj < 4; ++jj) u.v4[jj] = f2bf(accp[jj]);
        size_t eoff = ((size_t)(j0 >> 3) * 64 + b) * 8 + (j0 & 7);
        stc8(emb_sw + eoff, u.q);
        stc8(det_sw + eoff, 0ull);
        *(f32x4*)(det_fp0 + blk * 1024 + tid * 4) = (f32x4){0.f, 0.f, 0.f, 0.f};
    } else if (tid < 384) {   // swizzle obs(:, t=0, :) — row blk
        int g = tid - 256;
        const float* src = obs + (size_t)blk * T_ * 1024 + g * 8;
        bfrag v;
#pragma unroll
        for (int i = 0; i < 8; ++i) v[i] = (short)f2bf(src[i]);
        stc16b(obs_sw + ((size_t)g * 64 + blk) * 8, v);
    }
    gbar(gsync, blk, ep);

    float* dfp_in = det_fp0;
    float* dfp_out = det_fp1;

#pragma unroll 1
    for (int t = 0; t < T_; ++t) {
        const ushort_t* emb_t = emb_sw + ((size_t)t << 16);
        const ushort_t* det_t = det_sw + ((size_t)t << 16);
        ushort_t*       det_n = det_sw + ((size_t)(t + 1) << 16);
        const ushort_t* obs_t = obs_sw + ((size_t)t << 16);

        // ================= phase A: GRU =================
        {
            const int lane = tid & 63, w = tid >> 6;     // w in [0,8)
            const int kw = w >> 1, bw = w & 1;
            const int m = lane & 15, quad = lane >> 4;
            const int j0 = blk * 16;

            f32x4 acc[2][3][2];
#pragma unroll
            for (int a2 = 0; a2 < 2; ++a2)
#pragma unroll
                for (int g = 0; g < 3; ++g)
#pragma unroll
                    for (int n = 0; n < 2; ++n) acc[a2][g][n] = (f32x4){0.f, 0.f, 0.f, 0.f};

            const int kb0 = kw * 256;
            const ushort_t* arow[2][3];
#pragma unroll
            for (int g = 0; g < 3; ++g) {
                arow[0][g] = Wih + (size_t)(g * 1024 + j0 + m) * 1024 + kb0 + quad * 8;
                arow[1][g] = Whh + (size_t)(g * 1024 + j0 + m) * 1024 + kb0 + quad * 8;
            }
            const ushort_t* bx = emb_t + ((kb0 >> 3) + quad) * 512 + m * 8;
            const ushort_t* bh = det_t + ((kb0 >> 3) + quad) * 512 + m * 8;

#pragma unroll
            for (int it = 0; it < 8; ++it) {
                bfrag a[2][3], vx[2], vh[2];
#pragma unroll
                for (int g = 0; g < 3; ++g) {
                    a[0][g] = *(const bfrag*)(arow[0][g] + it * 32);
                    a[1][g] = *(const bfrag*)(arow[1][g] + it * 32);
                }
#pragma unroll
                for (int n = 0; n < 2; ++n) {
                    vx[n] = *(const bfrag*)(bx + it * 2048 + (bw * 2 + n) * 128);
                    vh[n] = *(const bfrag*)(bh + it * 2048 + (bw * 2 + n) * 128);
                }
#pragma unroll
                for (int g = 0; g < 3; ++g)
#pragma unroll
                    for (int n = 0; n < 2; ++n) {
                        acc[0][g][n] = __builtin_amdgcn_mfma_f32_16x16x32_bf16(a[0][g], vx[n], acc[0][g][n], 0, 0, 0);
                        acc[1][g][n] = __builtin_amdgcn_mfma_f32_16x16x32_bf16(a[1][g], vh[n], acc[1][g][n], 0, 0, 0);
                    }
            }

            // cross-wave reduce over kw: kw 1,3 dump to slot kw>>1; kw 0,2 add.
            // slab index = (a2*3+g)*4 + global_n, global_n = bw*2+n  (layout
            // identical to round 6 -> gate code unchanged, same sum tree).
            if (kw & 1) {
                float* dst = red + (kw >> 1) * 6144;
#pragma unroll
                for (int a2 = 0; a2 < 2; ++a2)
#pragma unroll
                    for (int g = 0; g < 3; ++g)
#pragma unroll
                        for (int n = 0; n < 2; ++n)
                            *(f32x4*)(dst + ((a2 * 3 + g) * 4 + bw * 2 + n) * 256 + lane * 4) = acc[a2][g][n];
            }
            __syncthreads();
            if (!(kw & 1)) {
                float* dst = red + (kw >> 1) * 6144;
#pragma unroll
                for (int a2 = 0; a2 < 2; ++a2)
#pragma unroll
                    for (int g = 0; g < 3; ++g)
#pragma unroll
                        for (int n = 0; n < 2; ++n) {
                            float* pp = dst + ((a2 * 3 + g) * 4 + bw * 2 + n) * 256 + lane * 4;
                            f32x4 v = *(const f32x4*)pp;
                            v += acc[a2][g][n];
                            *(f32x4*)pp = v;
                        }
            }
            __syncthreads();

            if (tid < 256) {   // gate phase: thread -> (b = tid>>2, jq = tid&3)
                int b = tid >> 2, jq = tid & 3;
                int nt = b >> 4, bl = b & 15;
                int lsrc = (jq * 16 + bl) * 4;
                float gg[2][3][4];
#pragma unroll
                for (int a2 = 0; a2 < 2; ++a2)
#pragma unroll
                    for (int g = 0; g < 3; ++g) {
                        f32x4 v0 = *(const f32x4*)(red + ((a2 * 3 + g) * 4 + nt) * 256 + lsrc);
                        f32x4 v1 = *(const f32x4*)(red + 6144 + ((a2 * 3 + g) * 4 + nt) * 256 + lsrc);
#pragma unroll
                        for (int i = 0; i < 4; ++i) gg[a2][g][i] = v0[i] + v1[i];
                    }
                f32x4 bi[3], bh2[3];
#pragma unroll
                for (int g = 0; g < 3; ++g) {
                    bi[g] = *(const f32x4*)(bih + g * 1024 + j0 + jq * 4);
                    bh2[g] = *(const f32x4*)(bhh + g * 1024 + j0 + jq * 4);
                }
                f32x4 h4;
                U8 dq;
#pragma unroll
                for (int i = 0; i < 4; ++i) {
                    int j = j0 + jq * 4 + i;
                    float r = sigmoidf_(gg[0][0][i] + bi[0][i] + gg[1][0][i] + bh2[0][i]);
                    float z = sigmoidf_(gg[0][1][i] + bi[1][i] + gg[1][1][i] + bh2[1][i]);
                    float n = tanhf(gg[0][2][i] + bi[2][i] + r * (gg[1][2][i] + bh2[2][i]));
                    float hp = dfp_in[j * 64 + b];
                    float h = (1.f - z) * n + z * hp;
                    h4[i] = h;
                    dq.v4[i] = f2bf(h);
                    dfp_out[j * 64 + b] = h;
                }
                *(f32x4*)(out + ((size_t)b * T_ + t) * OUTD + j0 + jq * 4) = h4;
                int kbase = j0 + jq * 4;
                stc8(det_n + ((size_t)(kbase >> 3) * 64 + b) * 8 + (kbase & 7), dq.q);
            }
        }
        gbar(gsync, blk, ep);

        // ================= phase B: pm1 / qm1 =================
        {
            const int lane = tid & 63, w = tid >> 6;
            const int kw = w >> 1, bw = w & 1;
            const int m = lane & 15, quad = lane >> 4;
            const bool isq = blk >= 32;
            const int j0 = (isq ? blk - 32 : blk) * 16;

            f32x4 acc[2];
            acc[0] = (f32x4){0.f, 0.f, 0.f, 0.f};
            acc[1] = (f32x4){0.f, 0.f, 0.f, 0.f};

            if (!isq) {
                const ushort_t* ar = Wp1b + (size_t)(j0 + m) * 1024 + kw * 256 + quad * 8;
                const ushort_t* bb = det_n + ((kw * 32) + quad) * 512 + m * 8;
#pragma unroll
                for (int it = 0; it < 8; ++it) {
                    bfrag a = *(const bfrag*)(ar + it * 32);
#pragma unroll
                    for (int n = 0; n < 2; ++n) {
                        bfrag v = *(const bfrag*)(bb + it * 2048 + (bw * 2 + n) * 128);
                        acc[n] = __builtin_amdgcn_mfma_f32_16x16x32_bf16(a, v, acc[n], 0, 0, 0);
                    }
                }
            } else {
                int kb0 = kw * 512;
                const ushort_t* bsrc = (kw < 2) ? (const ushort_t*)det_n : obs_t;
                int kloc = (kw < 2) ? kb0 : kb0 - 1024;
                const ushort_t* ar = Wq1b + (size_t)(j0 + m) * 2048 + kb0 + quad * 8;
                const ushort_t* bb = bsrc + ((kloc >> 3) + quad) * 512 + m * 8;
#pragma unroll
                for (int it = 0; it < 16; ++it) {
                    bfrag a = *(const bfrag*)(ar + it * 32);
#pragma unroll
                    for (int n = 0; n < 2; ++n) {
                        bfrag v = *(const bfrag*)(bb + it * 2048 + (bw * 2 + n) * 128);
                        acc[n] = __builtin_amdgcn_mfma_f32_16x16x32_bf16(a, v, acc[n], 0, 0, 0);
                    }
                }
            }
            // dump: slab = kw*4 + global_n  (same [4][4] layout as round 6)
#pragma unroll
            for (int n = 0; n < 2; ++n)
                *(f32x4*)(red + (kw * 4 + bw * 2 + n) * 256 + lane * 4) = acc[n];
            __syncthreads();

            if (tid < 256) {
                int b = tid >> 2, jq = tid & 3;
                int nt = b >> 4, lsrc = (jq * 16 + (b & 15)) * 4;
                f32x4 s = (f32x4){0.f, 0.f, 0.f, 0.f};
#pragma unroll
                for (int w2 = 0; w2 < 4; ++w2) s += *(const f32x4*)(red + (w2 * 4 + nt) * 256 + lsrc);
                f32x4 bv = *(const f32x4*)((isq ? bq1 : bp1) + j0 + jq * 4);
                f32x4 r;
#pragma unroll
                for (int i = 0; i < 4; ++i) r[i] = fmaxf(s[i] + bv[i], 0.f);
                stc16f((isq ? qm1 : pm1) + (size_t)b * 512 + j0 + jq * 4, r);
            }
        }
        gbar(gsync, blk, ep);

        // ======== phase C: heads + stats + emb(t+1) + obs(t+1) — 512 thr ====
        {
            float* s_p = red;                  // [512]
            float* s_q = red + 512;            // [512]
            float* s_in = red + 1152;          // [0,32) stoch, [32,96) act(t+1)
            float* ph = red + 1280;            // [2 khalf][128 outs]
            ushort_t* ush = (ushort_t*)(red + 1536);   // [1024] emb staging
            const int b = blk;
            if (tid < 128) ((f32x4*)s_p)[tid] = ldc16f(pm1 + (size_t)b * 512 + tid * 4);
            else if (tid < 256) ((f32x4*)s_q)[tid - 128] = ldc16f(qm1 + (size_t)b * 512 + (tid - 128) * 4);
            else if (tid < 384) {
                if (t + 1 < T_) {   // swizzle obs(:, t+1, :) row b
                    int g = tid - 256;
                    const float* src0 = obs + ((size_t)b * T_ + t + 1) * 1024 + g * 8;
                    bfrag v0;
#pragma unroll
                    for (int i = 0; i < 8; ++i) v0[i] = (short)f2bf(src0[i]);
                    stc16b(obs_sw + ((size_t)(t + 1) << 16) + ((size_t)g * 64 + b) * 8, v0);
                }
            } else if (tid < 448) {
                if (t + 1 < T_) s_in[32 + (tid - 384)] = act[((size_t)b * T_ + t + 1) * 64 + (tid - 384)];
            }
            __syncthreads();
            if (tid < 256) {   // head GEMV, K-split x2: kh covers g in [kh*32, kh*32+32)
                int kh = tid >> 7, head = (tid >> 6) & 1, o = tid & 63;
                const ushort_t* wp = W2sw + head * 32768 + o * 8 + kh * 32 * 512;
                const float* hv = (head ? s_q : s_p) + kh * 256;
                float acc2 = 0.f;
#pragma unroll 8
                for (int g = 0; g < 32; ++g) {
                    bfrag w8 = *(const bfrag*)(wp + g * 512);
#pragma unroll
                    for (int i2 = 0; i2 < 8; ++i2) acc2 += hv[g * 8 + i2] * bf2f((ushort_t)w8[i2]);
                }
                ph[kh * 128 + head * 64 + o] = acc2;
            }
            __syncthreads();
            if (tid < 64) {    // stats: combine K-halves + bias inline
                int s = tid & 31, isq = tid >> 5;
                const float* bias = isq ? bq2 : bp2;
                float mean = ph[isq * 64 + s] + ph[128 + isq * 64 + s] + bias[s];
                float raw  = ph[isq * 64 + 32 + s] + ph[128 + isq * 64 + 32 + s] + bias[32 + s];
                float sd = softplusf_(raw) + 1e-5f;
                float noise = (isq ? n_q : n_p)[((size_t)b * T_ + t) * 32 + s];
                float st = mean + sd * noise;
                float* o = out + ((size_t)b * T_ + t) * OUTD + 1024 + isq * 96;
                o[s] = mean;
                o[32 + s] = sd;
                o[64 + s] = st;
                if (isq) s_in[s] = st;
            }
            __syncthreads();
            if (t + 1 < T_) {   // emb(t+1): 2 j per thread, staged to LDS
                int j0e = tid * 2;
                float acc2[2];
                acc2[0] = bsa[j0e];
                acc2[1] = bsa[j0e + 1];
#pragma unroll
                for (int g = 0; g < 12; ++g) {
#pragma unroll
                    for (int jj = 0; jj < 2; ++jj) {
                        bfrag w8 = *(const bfrag*)(Wsasw + ((size_t)g * 1024 + j0e + jj) * 8);
#pragma unroll
                        for (int i2 = 0; i2 < 8; ++i2) acc2[jj] += s_in[g * 8 + i2] * bf2f((ushort_t)w8[i2]);
                    }
                }
                ush[j0e] = f2bf(fmaxf(acc2[0], 0.f));
                ush[j0e + 1] = f2bf(fmaxf(acc2[1], 0.f));
            }
            __syncthreads();
            if (t + 1 < T_ && tid < 128) {
                bfrag v = *(const bfrag*)(ush + tid * 8);
                stc16b(emb_sw + ((size_t)(t + 1) << 16) + ((size_t)tid * 64 + b) * 8, v);
            }
        }
        gbar(gsync, blk, ep);

        // swap block-private det_fp ping-pong
        float* tf = dfp_in; dfp_in = dfp_out; dfp_out = tf;
    }
}

extern "C" void kernel_launch(void* const* d_in, const int* in_sizes, int n_in,
                              void* d_out, int out_size, void* d_ws, size_t ws_size,
                              hipStream_t stream) {
    const float* obs = (const float*)d_in[0];
    const float* act = (const float*)d_in[1];
    const float* n_p = (const float*)d_in[2];
    const float* n_q = (const float*)d_in[3];
    const float* W_sa = (const float*)d_in[4];
    const float* b_sa = (const float*)d_in[5];
    const float* W_ih = (const float*)d_in[6];
    const float* b_ih = (const float*)d_in[7];
    const float* W_hh = (const float*)d_in[8];
    const float* b_hh = (const float*)d_in[9];
    const float* Wp1 = (const float*)d_in[10];
    const float* bp1 = (const float*)d_in[11];
    const float* Wp2 = (const float*)d_in[12];
    const float* bp2 = (const float*)d_in[13];
    const float* Wq1 = (const float*)d_in[14];
    const float* bq1 = (const float*)d_in[15];
    const float* Wq2 = (const float*)d_in[16];
    const float* bq2 = (const float*)d_in[17];
    float* out = (float*)d_out;

    if (ws_size < (size_t)115 * 1024 * 1024) return;

    char* p = (char*)d_ws;
    ushort_t* Wih_b = (ushort_t*)p;  p += (size_t)3145728 * 2;
    ushort_t* Whh_b = (ushort_t*)p;  p += (size_t)3145728 * 2;
    ushort_t* Wp1_b = (ushort_t*)p;  p += (size_t)524288 * 2;
    ushort_t* Wq1_b = (ushort_t*)p;  p += (size_t)1048576 * 2;
    ushort_t* W2sw  = (ushort_t*)p;  p += (size_t)65536 * 2;
    ushort_t* Wsasw = (ushort_t*)p;  p += (size_t)98304 * 2;
    float* pm1 = (float*)p; p += (size_t)32768 * 4;
    float* qm1 = (float*)p; p += (size_t)32768 * 4;
    float* det_fp0 = (float*)p; p += (size_t)65536 * 4;
    float* det_fp1 = (float*)p; p += (size_t)65536 * 4;
    unsigned* gsync = (unsigned*)p; p += (size_t)16384 * 4;
    ushort_t* emb_sw = (ushort_t*)p; p += (size_t)256 * 65536 * 2;   // [t][...]
    ushort_t* obs_sw = (ushort_t*)p; p += (size_t)256 * 65536 * 2;   // [t][...]
    ushort_t* det_sw = (ushort_t*)p; p += (size_t)257 * 65536 * 2;   // [t][...]

    kwprep<<<1024, 256, 0, stream>>>(W_ih, W_hh, Wp1, Wq1, Wp2, Wq2, W_sa,
                                     Wih_b, Whh_b, Wp1_b, Wq1_b, W2sw, Wsasw, gsync);
    krssm<<<NBLK, 512, 0, stream>>>(obs, act, n_p, n_q, W_sa, b_sa,
                                    Wih_b, Whh_b, b_ih, b_hh,
                                    Wp1_b, bp1, Wq1_b, bq1,
                                    W2sw, Wsasw, bp2, bq2,
                                    emb_sw, obs_sw, det_sw,
                                    det_fp0, det_fp1, pm1, qm1, out, gsync);
}